// Round 1
// baseline (4779.025 us; speedup 1.0000x reference)
//
#include <hip/hip_runtime.h>
#include <math.h>

#define PI_F 3.14159265358979323846f
#define TWOPI_F 6.283185307179586f

// ---------------- sizes ----------------
// pairs: 64 slots (32 batches x top-2)
// per pair: h = 64ch x 64 x 64 = 262144 floats (1MB)
// F/Fo per pair: 64 x 32kx x 16ky x 2 = 65536 floats
// G per pair: 64ci x 64x x 16ky x 2 = 131072 floats

__device__ __forceinline__ float gelu_f(float v) {
    float u = 0.7978845608028654f * (v + 0.044715f * v * v * v);
    return 0.5f * v * (1.f + tanhf(u));
}

// ---------------- twiddle tables ----------------
__global__ void init_tables_kernel(float* __restrict__ Wy, float* __restrict__ TWX,
                                   float* __restrict__ WY2) {
    int t = threadIdx.x;
    // Wy[y][2k,(2k+1)] = e^{-2pi i k y/64}, k<16   (forward y-DFT)
    for (int i = t; i < 1024; i += 256) {
        int y = i >> 4, k = i & 15;
        int m = (k * y) & 63;
        float a = -TWOPI_F * (float)m / 64.f;
        Wy[y * 32 + 2 * k]     = cosf(a);
        Wy[y * 32 + 2 * k + 1] = sinf(a);
    }
    // TWX[x][2kxm,(2kxm+1)] = e^{-2pi i kx x/64}, kx = kxm<16?kxm:kxm+32
    for (int i = t; i < 2048; i += 256) {
        int x = i >> 5, kxm = i & 31;
        int kx = kxm < 16 ? kxm : kxm + 32;
        int m = (kx * x) & 63;
        float a = -TWOPI_F * (float)m / 64.f;
        TWX[x * 64 + 2 * kxm]     = cosf(a);
        TWX[x * 64 + 2 * kxm + 1] = sinf(a);
    }
    // WY2[y][2k,(2k+1)] = s(k)/4096 * e^{+2pi i k y/64}, s(0)=1 else 2 (inverse y)
    for (int i = t; i < 1024; i += 256) {
        int y = i >> 4, k = i & 15;
        int m = (k * y) & 63;
        float a = TWOPI_F * (float)m / 64.f;
        float sc = (k == 0 ? 1.f : 2.f) / 4096.f;
        WY2[y * 32 + 2 * k]     = sc * cosf(a);
        WY2[y * 32 + 2 * k + 1] = sc * sinf(a);
    }
}

// ---------------- router: one block per batch ----------------
__global__ __launch_bounds__(256) void router_kernel(
    const float* __restrict__ x, const float* __restrict__ enc_w, const float* __restrict__ enc_b,
    const float* __restrict__ wqkv, const float* __restrict__ bqkv,
    const float* __restrict__ wo, const float* __restrict__ bo,
    const float* __restrict__ ln1g, const float* __restrict__ ln1b,
    const float* __restrict__ w1, const float* __restrict__ b1,
    const float* __restrict__ w2, const float* __restrict__ b2,
    const float* __restrict__ ln2g, const float* __restrict__ ln2b,
    const float* __restrict__ fcw, const float* __restrict__ fcb,
    float* __restrict__ rw)
{
    __shared__ float s[64][64];      // sequence state
    __shared__ float bufA[64][192];  // qkv / ffn-hidden cols 0..191
    __shared__ float bufB[64][64];   // scores / residual / ffn-hidden cols 192..255
    __shared__ float bufC[64][64];   // attn-out / ffn-out
    __shared__ float feat[64];
    __shared__ float logits[8];
    int b = blockIdx.x, t = threadIdx.x;

    // encode: s[w][d] = x[b,0,0,w]*enc_w[d] + enc_b[d]
    for (int i = t; i < 4096; i += 256) {
        int w_ = i >> 6, d = i & 63;
        s[w_][d] = x[b * 4096 + w_] * enc_w[d] + enc_b[d];
    }
    __syncthreads();

    for (int l = 0; l < 2; ++l) {
        const float* Wq = wqkv + l * 64 * 192;
        const float* Bq = bqkv + l * 192;
        for (int i = t; i < 64 * 192; i += 256) {
            int r = i / 192, c = i % 192;
            float acc = Bq[c];
            for (int k = 0; k < 64; ++k) acc += s[r][k] * Wq[k * 192 + c];
            bufA[r][c] = acc;
        }
        __syncthreads();
        for (int h = 0; h < 4; ++h) {
            for (int i = t; i < 4096; i += 256) {
                int qi = i >> 6, kj = i & 63;
                float acc = 0.f;
                for (int d = 0; d < 16; ++d)
                    acc += bufA[qi][h * 16 + d] * bufA[kj][64 + h * 16 + d];
                bufB[qi][kj] = acc * 0.25f;  // / sqrt(16)
            }
            __syncthreads();
            if (t < 64) {
                float m = -1e30f;
                for (int j = 0; j < 64; ++j) m = fmaxf(m, bufB[t][j]);
                float sum = 0.f;
                for (int j = 0; j < 64; ++j) { float e2 = expf(bufB[t][j] - m); bufB[t][j] = e2; sum += e2; }
                float inv = 1.f / sum;
                for (int j = 0; j < 64; ++j) bufB[t][j] *= inv;
            }
            __syncthreads();
            for (int i = t; i < 1024; i += 256) {
                int qi = i >> 4, d = i & 15;
                float acc = 0.f;
                for (int j = 0; j < 64; ++j) acc += bufB[qi][j] * bufA[j][128 + h * 16 + d];
                bufC[qi][h * 16 + d] = acc;
            }
            __syncthreads();
        }
        const float* Wo = wo + l * 4096;
        const float* Bo = bo + l * 64;
        for (int i = t; i < 4096; i += 256) {
            int r = i >> 6, c = i & 63;
            float acc = Bo[c];
            for (int k = 0; k < 64; ++k) acc += bufC[r][k] * Wo[k * 64 + c];
            bufB[r][c] = s[r][c] + acc;  // residual
        }
        __syncthreads();
        if (t < 64) {  // LN1
            float m = 0.f;
            for (int j = 0; j < 64; ++j) m += bufB[t][j];
            m *= (1.f / 64.f);
            float v = 0.f;
            for (int j = 0; j < 64; ++j) { float d = bufB[t][j] - m; v += d * d; }
            v *= (1.f / 64.f);
            float inv = rsqrtf(v + 1e-5f);
            for (int j = 0; j < 64; ++j)
                s[t][j] = (bufB[t][j] - m) * inv * ln1g[l * 64 + j] + ln1b[l * 64 + j];
        }
        __syncthreads();
        const float* W1 = w1 + l * 64 * 256;
        const float* B1 = b1 + l * 256;
        for (int i = t; i < 64 * 256; i += 256) {
            int r = i >> 8, c = i & 255;
            float acc = B1[c];
            for (int k = 0; k < 64; ++k) acc += s[r][k] * W1[k * 256 + c];
            acc = fmaxf(acc, 0.f);
            if (c < 192) bufA[r][c] = acc; else bufB[r][c - 192] = acc;
        }
        __syncthreads();
        const float* W2 = w2 + l * 256 * 64;
        const float* B2 = b2 + l * 64;
        for (int i = t; i < 4096; i += 256) {
            int r = i >> 6, c = i & 63;
            float acc = B2[c];
            for (int k = 0; k < 256; ++k) {
                float hv = (k < 192) ? bufA[r][k] : bufB[r][k - 192];
                acc += hv * W2[k * 64 + c];
            }
            bufC[r][c] = s[r][c] + acc;
        }
        __syncthreads();
        if (t < 64) {  // LN2
            float m = 0.f;
            for (int j = 0; j < 64; ++j) m += bufC[t][j];
            m *= (1.f / 64.f);
            float v = 0.f;
            for (int j = 0; j < 64; ++j) { float d = bufC[t][j] - m; v += d * d; }
            v *= (1.f / 64.f);
            float inv = rsqrtf(v + 1e-5f);
            for (int j = 0; j < 64; ++j)
                s[t][j] = (bufC[t][j] - m) * inv * ln2g[l * 64 + j] + ln2b[l * 64 + j];
        }
        __syncthreads();
    }
    if (t < 64) {
        float m = -1e30f;
        for (int r = 0; r < 64; ++r) m = fmaxf(m, s[r][t]);
        feat[t] = m;
    }
    __syncthreads();
    if (t < 8) {
        float acc = fcb[t];
        for (int k = 0; k < 64; ++k) acc += feat[k] * fcw[k * 8 + t];
        logits[t] = acc;
    }
    __syncthreads();
    if (t == 0) {
        int i0 = 0;
        for (int j = 1; j < 8; ++j) if (logits[j] > logits[i0]) i0 = j;
        int i1 = -1;
        for (int j = 0; j < 8; ++j) {
            if (j == i0) continue;
            if (i1 < 0 || logits[j] > logits[i1]) i1 = j;
        }
        float e1 = expf(logits[i1] - logits[i0]);
        float w0 = 1.f / (1.f + e1);
        float w1v = e1 / (1.f + e1);
        for (int j = 0; j < 8; ++j) rw[b * 8 + j] = 0.f;
        rw[b * 8 + i0] = w0;
        rw[b * 8 + i1] = w1v;
    }
}

// ---------------- build compact (b,e) pair list grouped by expert ----------------
__global__ void build_pairs_kernel(const float* __restrict__ rw, int* __restrict__ pair_b,
                                   int* __restrict__ pair_e, float* __restrict__ pair_w,
                                   int* __restrict__ estart) {
    __shared__ float r[256];
    __shared__ int cnt[8], off[9];
    int t = threadIdx.x;  // 64 threads
    for (int i = t; i < 256; i += 64) r[i] = rw[i];
    if (t < 64) { pair_b[t] = 0; pair_e[t] = 0; pair_w[t] = 0.f; }
    __syncthreads();
    if (t < 8) {
        int c = 0;
        for (int b = 0; b < 32; ++b) if (r[b * 8 + t] != 0.f) ++c;
        cnt[t] = c;
    }
    __syncthreads();
    if (t == 0) {
        int a = 0;
        for (int e = 0; e < 8; ++e) { off[e] = a; a += cnt[e]; }
        off[8] = a;
        for (int e = 0; e <= 8; ++e) estart[e] = off[e];
    }
    __syncthreads();
    if (t < 8) {
        int n = off[t];
        for (int b = 0; b < 32; ++b) {
            float w = r[b * 8 + t];
            if (w != 0.f) { pair_b[n] = b; pair_e[n] = t; pair_w[n] = w; ++n; }
        }
    }
}

// ---------------- lift: h0[co][xy] = x[b,0,xy]*lw[e,0,co] + lb[e,co] ----------------
__global__ __launch_bounds__(256) void lift_kernel(const float* __restrict__ x,
    const float* __restrict__ lw, const float* __restrict__ lb,
    const int* __restrict__ pair_b, const int* __restrict__ pair_e, float* __restrict__ hA) {
    int p = blockIdx.x, tile = blockIdx.y, t = threadIdx.x;
    int b = pair_b[p], e = pair_e[p];
    float* h = hA + (size_t)p * 262144;
    const float* xb = x + (size_t)b * 4096;
    for (int i = tile * 16384 + t; i < (tile + 1) * 16384; i += 256) {
        int co = i >> 12, xy = i & 4095;
        h[i] = xb[xy] * lw[e * 64 + co] + lb[e * 64 + co];
    }
}

// ---------------- forward y-DFT: per-lane row (p,ci,x), uniform Wy ----------------
__global__ __launch_bounds__(256) void ydft_kernel(const float* __restrict__ h,
    const float* __restrict__ Wy, float* __restrict__ G) {
    int row = blockIdx.x * 256 + threadIdx.x;  // (p,ci,x) = 262144 rows
    const float* src = h + (size_t)row * 64;
    float acc[32];
#pragma unroll
    for (int c = 0; c < 32; ++c) acc[c] = 0.f;
    for (int yc = 0; yc < 4; ++yc) {
        float4 r0 = *(const float4*)(src + yc * 16);
        float4 r1 = *(const float4*)(src + yc * 16 + 4);
        float4 r2 = *(const float4*)(src + yc * 16 + 8);
        float4 r3 = *(const float4*)(src + yc * 16 + 12);
        float rr[16] = {r0.x, r0.y, r0.z, r0.w, r1.x, r1.y, r1.z, r1.w,
                        r2.x, r2.y, r2.z, r2.w, r3.x, r3.y, r3.z, r3.w};
        const float* wb = Wy + yc * 16 * 32;
#pragma unroll
        for (int j = 0; j < 16; ++j) {
            float a = rr[j];
            const float* wr = wb + j * 32;
#pragma unroll
            for (int c = 0; c < 32; ++c) acc[c] += a * wr[c];
        }
    }
    float* dst = G + (size_t)row * 32;
#pragma unroll
    for (int c = 0; c < 32; c += 4)
        *(float4*)(dst + c) = make_float4(acc[c], acc[c + 1], acc[c + 2], acc[c + 3]);
}

// ---------------- forward x-DFT: per-lane row (p,ci,ky), uniform TWX ----------------
__global__ __launch_bounds__(256) void xdft_kernel(const float* __restrict__ G,
    const float* __restrict__ TWX, float* __restrict__ F) {
    int row = blockIdx.x * 256 + threadIdx.x;  // 65536 rows
    int p = row >> 10, ci = (row >> 4) & 63, ky = row & 15;
    const float* gbase = G + ((size_t)(p * 64 + ci) * 64) * 32 + ky * 2;
    float ar[32], ai[32];
#pragma unroll
    for (int c = 0; c < 32; ++c) { ar[c] = 0.f; ai[c] = 0.f; }
    for (int xc = 0; xc < 8; ++xc) {
        float gr[8], gi[8];
#pragma unroll
        for (int j = 0; j < 8; ++j) {
            float2 v = *(const float2*)(gbase + (size_t)(xc * 8 + j) * 32);
            gr[j] = v.x; gi[j] = v.y;
        }
#pragma unroll
        for (int j = 0; j < 8; ++j) {
            const float* tx = TWX + (xc * 8 + j) * 64;
#pragma unroll
            for (int k = 0; k < 32; ++k) {
                float c_ = tx[2 * k], s_ = tx[2 * k + 1];
                ar[k] += gr[j] * c_ - gi[j] * s_;
                ai[k] += gr[j] * s_ + gi[j] * c_;
            }
        }
    }
    float* fb = F + ((size_t)(p * 64 + ci) * 512 + ky) * 2;
#pragma unroll
    for (int k = 0; k < 32; ++k) { fb[k * 32] = ar[k]; fb[k * 32 + 1] = ai[k]; }
}

// ---------------- spectral multiply: block (e,kxm), complex 64x64 per mode ----------------
__global__ __launch_bounds__(256) void spectral_kernel(
    const float* __restrict__ F, float* __restrict__ Fo,
    const float* __restrict__ w1, const float* __restrict__ w2,
    const int* __restrict__ estart, int l)
{
    int e = blockIdx.x, kxm = blockIdx.y, t = threadIdx.x;
    int p0 = estart[e], ne = estart[e + 1] - p0;
    if (ne == 0) return;
    __shared__ float Ws[8 * 2112];  // [ci][co][ky*2] stride-33 padded
    __shared__ float Fs[2048];      // [pl][ci][ky*2]
    const float* wsrc = (kxm < 16)
        ? (w1 + (size_t)(e * 4 + l) * 2097152 + (size_t)kxm * 32)
        : (w2 + (size_t)(e * 4 + l) * 2097152 + (size_t)(kxm - 16) * 32);
    int co = t & 63, q = t >> 6;
    for (int pc = 0; pc < ne; pc += 8) {
        float acc[8][8];
#pragma unroll
        for (int a = 0; a < 8; ++a)
#pragma unroll
            for (int bj = 0; bj < 8; ++bj) acc[a][bj] = 0.f;
        for (int cc = 0; cc < 64; cc += 8) {
            __syncthreads();
            for (int i = t; i < 16384; i += 256) {
                int ci = i >> 11, c2 = (i >> 5) & 63, f = i & 31;
                Ws[ci * 2112 + c2 * 33 + f] =
                    wsrc[(size_t)(cc + ci) * 32768 + (size_t)c2 * 512 + f];
            }
            for (int i = t; i < 2048; i += 256) {
                int pl = i >> 8, ci = (i >> 5) & 7, f = i & 31;
                int pg = pc + pl;
                Fs[i] = (pg < ne)
                    ? F[(size_t)(p0 + pg) * 65536 + (size_t)(cc + ci) * 1024 + kxm * 32 + f]
                    : 0.f;
            }
            __syncthreads();
            for (int ci = 0; ci < 8; ++ci) {
                float wr[4], wi[4];
#pragma unroll
                for (int j = 0; j < 4; ++j) {
                    wr[j] = Ws[ci * 2112 + co * 33 + (q * 4 + j) * 2];
                    wi[j] = Ws[ci * 2112 + co * 33 + (q * 4 + j) * 2 + 1];
                }
#pragma unroll
                for (int pl = 0; pl < 8; ++pl) {
#pragma unroll
                    for (int j = 0; j < 4; ++j) {
                        float fr = Fs[pl * 256 + ci * 32 + (q * 4 + j) * 2];
                        float fi = Fs[pl * 256 + ci * 32 + (q * 4 + j) * 2 + 1];
                        acc[pl][2 * j]     += fr * wr[j] - fi * wi[j];
                        acc[pl][2 * j + 1] += fr * wi[j] + fi * wr[j];
                    }
                }
            }
        }
#pragma unroll
        for (int pl = 0; pl < 8; ++pl) {
            if (pc + pl < ne) {
                float* dst = Fo + (size_t)(p0 + pc + pl) * 65536 + (size_t)co * 1024
                             + kxm * 32 + q * 8;
#pragma unroll
                for (int jj = 0; jj < 8; ++jj) dst[jj] = acc[pl][jj];
            }
        }
    }
}

// ---------------- 1x1 conv (skip / proj1): dst = maybe_gelu(W^T src + B) ----------------
__global__ __launch_bounds__(256) void conv1x1_kernel(
    const float* __restrict__ src, float* __restrict__ dst,
    const float* __restrict__ Wall, const float* __restrict__ Ball,
    const int* __restrict__ pair_e, int wmul, int wadd, int do_gelu)
{
    int p = blockIdx.x, tile = blockIdx.y, t = threadIdx.x;
    int e = pair_e[p];
    int widx = e * wmul + wadd;
    const float* W = Wall + (size_t)widx * 4096;
    const float* B = Ball + widx * 64;
    const float* s = src + (size_t)p * 262144 + tile * 256 + t;
    float acc[64];
#pragma unroll
    for (int c = 0; c < 64; ++c) acc[c] = 0.f;
    for (int ci = 0; ci < 64; ++ci) {
        float hv = s[(size_t)ci * 4096];
        const float* wr = W + ci * 64;
#pragma unroll
        for (int c = 0; c < 64; ++c) acc[c] += hv * wr[c];
    }
    float* d = dst + (size_t)p * 262144 + tile * 256 + t;
    for (int c = 0; c < 64; ++c) {
        float v = acc[c] + B[c];
        if (do_gelu) v = gelu_f(v);
        d[(size_t)c * 4096] = v;
    }
}

// ---------------- inverse x + inverse y + add skip + gelu ----------------
// wave = (p,co), lane = x. dst already holds the skip value; we add synthesis.
__global__ __launch_bounds__(256) void inv_kernel(
    const float* __restrict__ Fo, const float* __restrict__ WY2,
    float* __restrict__ dst_h, int do_gelu)
{
    __shared__ float tw[128];
    int t = threadIdx.x;
    if (t < 64) {
        float a = TWOPI_F * (float)t / 64.f;
        tw[2 * t] = cosf(a);
        tw[2 * t + 1] = sinf(a);
    }
    __syncthreads();
    int wid = __builtin_amdgcn_readfirstlane((int)(blockIdx.x * 4) + (t >> 6));
    int p = wid >> 6, co = wid & 63;
    int x = t & 63;
    const float* fo = Fo + (size_t)p * 65536 + (size_t)co * 1024;
    float Tr[16], Ti[16];
#pragma unroll
    for (int k = 0; k < 16; ++k) { Tr[k] = 0.f; Ti[k] = 0.f; }
    for (int kxm = 0; kxm < 32; ++kxm) {
        int kx = kxm < 16 ? kxm : kxm + 32;
        int idx = (kx * x) & 63;
        float c_ = tw[2 * idx], s_ = tw[2 * idx + 1];
        const float* fr = fo + kxm * 32;
#pragma unroll
        for (int k = 0; k < 16; ++k) {
            float vr = fr[2 * k], vi = fr[2 * k + 1];
            Tr[k] += vr * c_ - vi * s_;
            Ti[k] += vr * s_ + vi * c_;
        }
    }
    float* out = dst_h + (size_t)p * 262144 + (size_t)co * 4096 + (size_t)x * 64;
    for (int yc = 0; yc < 8; ++yc) {
        float vals[8];
#pragma unroll
        for (int j = 0; j < 8; ++j) {
            int y = yc * 8 + j;
            const float* wr = WY2 + y * 32;
            float acc = 0.f;
#pragma unroll
            for (int k = 0; k < 16; ++k) acc += Tr[k] * wr[2 * k] - Ti[k] * wr[2 * k + 1];
            vals[j] = acc;
        }
#pragma unroll
        for (int j = 0; j < 8; ++j) {
            float v = out[yc * 8 + j] + vals[j];
            if (do_gelu) v = gelu_f(v);
            vals[j] = v;
        }
        *(float4*)(out + yc * 8)     = make_float4(vals[0], vals[1], vals[2], vals[3]);
        *(float4*)(out + yc * 8 + 4) = make_float4(vals[4], vals[5], vals[6], vals[7]);
    }
}

// ---------------- proj2 + weighted accumulate into out ----------------
__global__ __launch_bounds__(256) void proj2_kernel(
    const float* __restrict__ hsrc, const float* __restrict__ p2w, const float* __restrict__ p2b,
    const int* __restrict__ pair_b, const int* __restrict__ pair_e,
    const float* __restrict__ pw, float* __restrict__ out)
{
    int p = blockIdx.x, tile = blockIdx.y, t = threadIdx.x;
    int b = pair_b[p], e = pair_e[p];
    float wgt = pw[p];
    const float* h = hsrc + (size_t)p * 262144 + tile * 256 + t;
    const float* w2 = p2w + e * 64;
    float acc = p2b[e];
#pragma unroll
    for (int c = 0; c < 64; ++c) acc += h[(size_t)c * 4096] * w2[c];
    atomicAdd(out + (size_t)b * 4096 + tile * 256 + t, wgt * acc);
}

// ---------------- launch ----------------
extern "C" void kernel_launch(void* const* d_in, const int* in_sizes, int n_in,
                              void* d_out, int out_size, void* d_ws, size_t ws_size,
                              hipStream_t stream) {
    const float* x    = (const float*)d_in[0];
    const float* encw = (const float*)d_in[1];
    const float* encb = (const float*)d_in[2];
    const float* wqkv = (const float*)d_in[3];
    const float* bqkv = (const float*)d_in[4];
    const float* wo   = (const float*)d_in[5];
    const float* bo   = (const float*)d_in[6];
    const float* ln1g = (const float*)d_in[7];
    const float* ln1b = (const float*)d_in[8];
    const float* fw1  = (const float*)d_in[9];
    const float* fb1  = (const float*)d_in[10];
    const float* fw2  = (const float*)d_in[11];
    const float* fb2  = (const float*)d_in[12];
    const float* ln2g = (const float*)d_in[13];
    const float* ln2b = (const float*)d_in[14];
    const float* fcw  = (const float*)d_in[15];
    const float* fcb  = (const float*)d_in[16];
    const float* lw   = (const float*)d_in[17];
    const float* lb   = (const float*)d_in[18];
    const float* sw1  = (const float*)d_in[19];
    const float* sw2  = (const float*)d_in[20];
    const float* skw  = (const float*)d_in[21];
    const float* skb  = (const float*)d_in[22];
    const float* p1w  = (const float*)d_in[23];
    const float* p1b  = (const float*)d_in[24];
    const float* p2w  = (const float*)d_in[25];
    const float* p2b  = (const float*)d_in[26];
    float* out = (float*)d_out;

    // workspace layout (floats)
    float* wsf    = (float*)d_ws;
    float* rw     = wsf;               // 256
    float* pair_w = wsf + 256;         // 64
    int*   ipart  = (int*)(wsf + 320);
    int* pair_b = ipart;               // 64
    int* pair_e = ipart + 64;          // 64
    int* estart = ipart + 128;         // 9
    float* Wy  = wsf + 512;            // 2048
    float* TWX = wsf + 2560;           // 4096
    float* WY2 = wsf + 6656;           // 2048 (ends 8704)
    float* hA  = wsf + 16384;                       // 64 * 262144
    float* hB  = hA + (size_t)64 * 262144;          // 64 * 262144
    float* F   = hB + (size_t)64 * 262144;          // 64 * 65536
    float* G   = F + (size_t)64 * 65536;            // 64 * 131072 (Fo aliases G)
    float* Fo  = G;
    size_t need = (16384 + 2ull * 64 * 262144 + 64ull * 65536 + 64ull * 131072) * 4;
    if (ws_size < need) return;  // workspace too small: bail (fails validation loudly)

    hipMemsetAsync(d_out, 0, (size_t)out_size * sizeof(float), stream);
    init_tables_kernel<<<1, 256, 0, stream>>>(Wy, TWX, WY2);
    router_kernel<<<32, 256, 0, stream>>>(x, encw, encb, wqkv, bqkv, wo, bo, ln1g, ln1b,
                                          fw1, fb1, fw2, fb2, ln2g, ln2b, fcw, fcb, rw);
    build_pairs_kernel<<<1, 64, 0, stream>>>(rw, pair_b, pair_e, pair_w, estart);
    lift_kernel<<<dim3(64, 16), 256, 0, stream>>>(x, lw, lb, pair_b, pair_e, hA);
    for (int l = 0; l < 4; ++l) {
        float* cur = (l & 1) ? hB : hA;
        float* nxt = (l & 1) ? hA : hB;
        ydft_kernel<<<1024, 256, 0, stream>>>(cur, Wy, G);
        xdft_kernel<<<256, 256, 0, stream>>>(G, TWX, F);
        spectral_kernel<<<dim3(8, 32), 256, 0, stream>>>(F, Fo, sw1, sw2, estart, l);
        conv1x1_kernel<<<dim3(64, 16), 256, 0, stream>>>(cur, nxt, skw, skb, pair_e, 4, l, 0);
        inv_kernel<<<1024, 256, 0, stream>>>(Fo, WY2, nxt, (l < 3) ? 1 : 0);
    }
    conv1x1_kernel<<<dim3(64, 16), 256, 0, stream>>>(hA, hB, p1w, p1b, pair_e, 1, 0, 1);
    proj2_kernel<<<dim3(64, 16), 256, 0, stream>>>(hB, p2w, p2b, pair_b, pair_e, pair_w, out);
}

// Round 2
// 3823.744 us; speedup vs baseline: 1.2498x; 1.2498x over previous
//
#include <hip/hip_runtime.h>
#include <math.h>

#define TWOPI_F 6.283185307179586f

__device__ __forceinline__ float gelu_f(float v) {
    float u = 0.7978845608028654f * (v + 0.044715f * v * v * v);
    return 0.5f * v * (1.f + tanhf(u));
}

// ---------------- twiddle tables ----------------
__global__ void init_tables_kernel(float* __restrict__ Wy, float* __restrict__ TWX,
                                   float* __restrict__ WY2) {
    int t = threadIdx.x;
    for (int i = t; i < 1024; i += 256) {
        int y = i >> 4, k = i & 15;
        int m = (k * y) & 63;
        float a = -TWOPI_F * (float)m / 64.f;
        Wy[y * 32 + 2 * k]     = cosf(a);
        Wy[y * 32 + 2 * k + 1] = sinf(a);
    }
    for (int i = t; i < 2048; i += 256) {
        int x = i >> 5, kxm = i & 31;
        int kx = kxm < 16 ? kxm : kxm + 32;
        int m = (kx * x) & 63;
        float a = -TWOPI_F * (float)m / 64.f;
        TWX[x * 64 + 2 * kxm]     = cosf(a);
        TWX[x * 64 + 2 * kxm + 1] = sinf(a);
    }
    for (int i = t; i < 1024; i += 256) {
        int y = i >> 4, k = i & 15;
        int m = (k * y) & 63;
        float a = TWOPI_F * (float)m / 64.f;
        float sc = (k == 0 ? 1.f : 2.f) / 4096.f;
        WY2[y * 32 + 2 * k]     = sc * cosf(a);
        WY2[y * 32 + 2 * k + 1] = sc * sinf(a);
    }
}

// ---------------- router: one block per batch ----------------
__global__ __launch_bounds__(256) void router_kernel(
    const float* __restrict__ x, const float* __restrict__ enc_w, const float* __restrict__ enc_b,
    const float* __restrict__ wqkv, const float* __restrict__ bqkv,
    const float* __restrict__ wo, const float* __restrict__ bo,
    const float* __restrict__ ln1g, const float* __restrict__ ln1b,
    const float* __restrict__ w1, const float* __restrict__ b1,
    const float* __restrict__ w2, const float* __restrict__ b2,
    const float* __restrict__ ln2g, const float* __restrict__ ln2b,
    const float* __restrict__ fcw, const float* __restrict__ fcb,
    float* __restrict__ rw)
{
    __shared__ float s[64][64];
    __shared__ float bufA[64][192];
    __shared__ float bufB[64][64];
    __shared__ float bufC[64][64];
    __shared__ float feat[64];
    __shared__ float logits[8];
    int b = blockIdx.x, t = threadIdx.x;

    for (int i = t; i < 4096; i += 256) {
        int w_ = i >> 6, d = i & 63;
        s[w_][d] = x[b * 4096 + w_] * enc_w[d] + enc_b[d];
    }
    __syncthreads();

    for (int l = 0; l < 2; ++l) {
        const float* Wq = wqkv + l * 64 * 192;
        const float* Bq = bqkv + l * 192;
        for (int i = t; i < 64 * 192; i += 256) {
            int r = i / 192, c = i % 192;
            float acc = Bq[c];
            for (int k = 0; k < 64; ++k) acc += s[r][k] * Wq[k * 192 + c];
            bufA[r][c] = acc;
        }
        __syncthreads();
        for (int h = 0; h < 4; ++h) {
            for (int i = t; i < 4096; i += 256) {
                int qi = i >> 6, kj = i & 63;
                float acc = 0.f;
                for (int d = 0; d < 16; ++d)
                    acc += bufA[qi][h * 16 + d] * bufA[kj][64 + h * 16 + d];
                bufB[qi][kj] = acc * 0.25f;
            }
            __syncthreads();
            if (t < 64) {
                float m = -1e30f;
                for (int j = 0; j < 64; ++j) m = fmaxf(m, bufB[t][j]);
                float sum = 0.f;
                for (int j = 0; j < 64; ++j) { float e2 = expf(bufB[t][j] - m); bufB[t][j] = e2; sum += e2; }
                float inv = 1.f / sum;
                for (int j = 0; j < 64; ++j) bufB[t][j] *= inv;
            }
            __syncthreads();
            for (int i = t; i < 1024; i += 256) {
                int qi = i >> 4, d = i & 15;
                float acc = 0.f;
                for (int j = 0; j < 64; ++j) acc += bufB[qi][j] * bufA[j][128 + h * 16 + d];
                bufC[qi][h * 16 + d] = acc;
            }
            __syncthreads();
        }
        const float* Wo = wo + l * 4096;
        const float* Bo = bo + l * 64;
        for (int i = t; i < 4096; i += 256) {
            int r = i >> 6, c = i & 63;
            float acc = Bo[c];
            for (int k = 0; k < 64; ++k) acc += bufC[r][k] * Wo[k * 64 + c];
            bufB[r][c] = s[r][c] + acc;
        }
        __syncthreads();
        if (t < 64) {
            float m = 0.f;
            for (int j = 0; j < 64; ++j) m += bufB[t][j];
            m *= (1.f / 64.f);
            float v = 0.f;
            for (int j = 0; j < 64; ++j) { float d = bufB[t][j] - m; v += d * d; }
            v *= (1.f / 64.f);
            float inv = rsqrtf(v + 1e-5f);
            for (int j = 0; j < 64; ++j)
                s[t][j] = (bufB[t][j] - m) * inv * ln1g[l * 64 + j] + ln1b[l * 64 + j];
        }
        __syncthreads();
        const float* W1 = w1 + l * 64 * 256;
        const float* B1 = b1 + l * 256;
        for (int i = t; i < 64 * 256; i += 256) {
            int r = i >> 8, c = i & 255;
            float acc = B1[c];
            for (int k = 0; k < 64; ++k) acc += s[r][k] * W1[k * 256 + c];
            acc = fmaxf(acc, 0.f);
            if (c < 192) bufA[r][c] = acc; else bufB[r][c - 192] = acc;
        }
        __syncthreads();
        const float* W2 = w2 + l * 256 * 64;
        const float* B2 = b2 + l * 64;
        for (int i = t; i < 4096; i += 256) {
            int r = i >> 6, c = i & 63;
            float acc = B2[c];
            for (int k = 0; k < 256; ++k) {
                float hv = (k < 192) ? bufA[r][k] : bufB[r][k - 192];
                acc += hv * W2[k * 64 + c];
            }
            bufC[r][c] = s[r][c] + acc;
        }
        __syncthreads();
        if (t < 64) {
            float m = 0.f;
            for (int j = 0; j < 64; ++j) m += bufC[t][j];
            m *= (1.f / 64.f);
            float v = 0.f;
            for (int j = 0; j < 64; ++j) { float d = bufC[t][j] - m; v += d * d; }
            v *= (1.f / 64.f);
            float inv = rsqrtf(v + 1e-5f);
            for (int j = 0; j < 64; ++j)
                s[t][j] = (bufC[t][j] - m) * inv * ln2g[l * 64 + j] + ln2b[l * 64 + j];
        }
        __syncthreads();
    }
    if (t < 64) {
        float m = -1e30f;
        for (int r = 0; r < 64; ++r) m = fmaxf(m, s[r][t]);
        feat[t] = m;
    }
    __syncthreads();
    if (t < 8) {
        float acc = fcb[t];
        for (int k = 0; k < 64; ++k) acc += feat[k] * fcw[k * 8 + t];
        logits[t] = acc;
    }
    __syncthreads();
    if (t == 0) {
        int i0 = 0;
        for (int j = 1; j < 8; ++j) if (logits[j] > logits[i0]) i0 = j;
        int i1 = -1;
        for (int j = 0; j < 8; ++j) {
            if (j == i0) continue;
            if (i1 < 0 || logits[j] > logits[i1]) i1 = j;
        }
        float e1 = expf(logits[i1] - logits[i0]);
        float w0 = 1.f / (1.f + e1);
        float w1v = e1 / (1.f + e1);
        for (int j = 0; j < 8; ++j) rw[b * 8 + j] = 0.f;
        rw[b * 8 + i0] = w0;
        rw[b * 8 + i1] = w1v;
    }
}

// ---------------- build compact (b,e) pair list grouped by expert ----------------
__global__ void build_pairs_kernel(const float* __restrict__ rw, int* __restrict__ pair_b,
                                   int* __restrict__ pair_e, float* __restrict__ pair_w,
                                   int* __restrict__ estart) {
    __shared__ float r[256];
    __shared__ int cnt[8], off[9];
    int t = threadIdx.x;
    for (int i = t; i < 256; i += 64) r[i] = rw[i];
    if (t < 64) { pair_b[t] = 0; pair_e[t] = 0; pair_w[t] = 0.f; }
    __syncthreads();
    if (t < 8) {
        int c = 0;
        for (int b = 0; b < 32; ++b) if (r[b * 8 + t] != 0.f) ++c;
        cnt[t] = c;
    }
    __syncthreads();
    if (t == 0) {
        int a = 0;
        for (int e = 0; e < 8; ++e) { off[e] = a; a += cnt[e]; }
        off[8] = a;
        for (int e = 0; e <= 8; ++e) estart[e] = off[e];
    }
    __syncthreads();
    if (t < 8) {
        int n = off[t];
        for (int b = 0; b < 32; ++b) {
            float w = r[b * 8 + t];
            if (w != 0.f) { pair_b[n] = b; pair_e[n] = t; pair_w[n] = w; ++n; }
        }
    }
}

// ---------------- lift ----------------
__global__ __launch_bounds__(256) void lift_kernel(const float* __restrict__ x,
    const float* __restrict__ lw, const float* __restrict__ lb,
    const int* __restrict__ pair_b, const int* __restrict__ pair_e, float* __restrict__ hA) {
    int p = blockIdx.x, tile = blockIdx.y, t = threadIdx.x;
    int b = pair_b[p], e = pair_e[p];
    float* h = hA + (size_t)p * 262144;
    const float* xb = x + (size_t)b * 4096;
    for (int i = tile * 16384 + t; i < (tile + 1) * 16384; i += 256) {
        int co = i >> 12, xy = i & 4095;
        h[i] = xb[xy] * lw[e * 64 + co] + lb[e * 64 + co];
    }
}

// ---------------- forward y-DFT ----------------
__global__ __launch_bounds__(256) void ydft_kernel(const float* __restrict__ h,
    const float* __restrict__ Wy, float* __restrict__ G) {
    int row = blockIdx.x * 256 + threadIdx.x;  // (p,ci,x) = 262144 rows
    const float* src = h + (size_t)row * 64;
    float acc[32];
#pragma unroll
    for (int c = 0; c < 32; ++c) acc[c] = 0.f;
    for (int yc = 0; yc < 4; ++yc) {
        float4 r0 = *(const float4*)(src + yc * 16);
        float4 r1 = *(const float4*)(src + yc * 16 + 4);
        float4 r2 = *(const float4*)(src + yc * 16 + 8);
        float4 r3 = *(const float4*)(src + yc * 16 + 12);
        float rr[16] = {r0.x, r0.y, r0.z, r0.w, r1.x, r1.y, r1.z, r1.w,
                        r2.x, r2.y, r2.z, r2.w, r3.x, r3.y, r3.z, r3.w};
        const float* wb = Wy + yc * 16 * 32;
#pragma unroll
        for (int j = 0; j < 16; ++j) {
            float a = rr[j];
            const float* wr = wb + j * 32;
#pragma unroll
            for (int c = 0; c < 32; ++c) acc[c] += a * wr[c];
        }
    }
    float* dst = G + (size_t)row * 32;
#pragma unroll
    for (int c = 0; c < 32; c += 4)
        *(float4*)(dst + c) = make_float4(acc[c], acc[c + 1], acc[c + 2], acc[c + 3]);
}

// ---------------- forward x-DFT: kx split in halves, 512 blocks ----------------
__global__ __launch_bounds__(256) void xdft_kernel(const float* __restrict__ G,
    const float* __restrict__ TWX, float* __restrict__ F) {
    int gid = blockIdx.x * 256 + threadIdx.x;  // 131072 threads
    int kxh = gid >> 16;
    int rid = gid & 65535;
    int p = rid >> 10, ci = (rid >> 4) & 63, ky = rid & 15;
    const float* gbase = G + (size_t)(p * 64 + ci) * 2048 + ky * 2;
    float ar[16], ai[16];
#pragma unroll
    for (int c = 0; c < 16; ++c) { ar[c] = 0.f; ai[c] = 0.f; }
    for (int xc = 0; xc < 8; ++xc) {
        float gr[8], gi[8];
#pragma unroll
        for (int j = 0; j < 8; ++j) {
            float2 v = *(const float2*)(gbase + (size_t)(xc * 8 + j) * 32);
            gr[j] = v.x; gi[j] = v.y;
        }
#pragma unroll
        for (int j = 0; j < 8; ++j) {
            const float* tx = TWX + (xc * 8 + j) * 64 + kxh * 32;
#pragma unroll
            for (int k = 0; k < 16; ++k) {
                float c_ = tx[2 * k], s_ = tx[2 * k + 1];
                ar[k] += gr[j] * c_ - gi[j] * s_;
                ai[k] += gr[j] * s_ + gi[j] * c_;
            }
        }
    }
    float* fb = F + (size_t)(p * 64 + ci) * 1024 + kxh * 512 + ky * 2;
#pragma unroll
    for (int k = 0; k < 16; ++k) { fb[k * 32] = ar[k]; fb[k * 32 + 1] = ai[k]; }
}

// ---------------- spectral multiply v2: zero-LDS weight streaming ----------------
// grid (8 experts, 32 kx-modes, 2 ky-halves), block 256 = 64 co x 4 ky-quarters.
// W streamed global->reg coalesced float4; F via wave-uniform scalar loads.
__global__ __launch_bounds__(256) void spectral_kernel(
    const float* __restrict__ F, float* __restrict__ Fo,
    const float* __restrict__ w1, const float* __restrict__ w2,
    const int* __restrict__ estart, int l)
{
    int e = blockIdx.x, kxm = blockIdx.y, kyh = blockIdx.z;
    int p0 = estart[e], ne = estart[e + 1] - p0;
    if (ne == 0) return;
    int t = threadIdx.x;
    int co = t & 63;
    int q = __builtin_amdgcn_readfirstlane(t >> 6);  // ky quarter, wave-uniform

    const float* wsrc = (kxm < 16)
        ? (w1 + (size_t)(e * 4 + l) * 2097152 + (size_t)kxm * 32)
        : (w2 + (size_t)(e * 4 + l) * 2097152 + (size_t)(kxm - 16) * 32);
    const float* Wb = wsrc + (size_t)co * 512 + kyh * 16 + q * 4;            // per-lane
    const float* Fb = F + (size_t)p0 * 65536 + kxm * 32 + kyh * 16 + q * 4;  // uniform
    float* Fob = Fo + (size_t)p0 * 65536 + (size_t)co * 1024 + kxm * 32 + kyh * 16 + q * 4;

    for (int pc = 0; pc < ne; pc += 8) {
        int np = ne - pc; if (np > 8) np = 8;
        float4 acc[8];
#pragma unroll
        for (int p = 0; p < 8; ++p) acc[p] = make_float4(0.f, 0.f, 0.f, 0.f);
#pragma unroll 4
        for (int ci = 0; ci < 64; ++ci) {
            float4 wv = *(const float4*)(Wb + (size_t)ci * 32768);
#pragma unroll
            for (int p = 0; p < 8; ++p) {
                int pp = pc + (p < np ? p : np - 1);  // clamp: safe load, unstored lanes
                float4 fv = *(const float4*)(Fb + (size_t)pp * 65536 + (size_t)ci * 1024);
                acc[p].x += fv.x * wv.x - fv.y * wv.y;
                acc[p].y += fv.x * wv.y + fv.y * wv.x;
                acc[p].z += fv.z * wv.z - fv.w * wv.w;
                acc[p].w += fv.z * wv.w + fv.w * wv.z;
            }
        }
#pragma unroll
        for (int p = 0; p < 8; ++p) {
            if (p < np)
                *(float4*)(Fob + (size_t)(pc + p) * 65536) = acc[p];
        }
    }
}

// ---------------- 1x1 conv (skip / proj1) ----------------
__global__ __launch_bounds__(256) void conv1x1_kernel(
    const float* __restrict__ src, float* __restrict__ dst,
    const float* __restrict__ Wall, const float* __restrict__ Ball,
    const int* __restrict__ pair_e, int wmul, int wadd, int do_gelu)
{
    int p = blockIdx.x, tile = blockIdx.y, t = threadIdx.x;
    int e = pair_e[p];
    int widx = e * wmul + wadd;
    const float* W = Wall + (size_t)widx * 4096;
    const float* B = Ball + widx * 64;
    const float* s = src + (size_t)p * 262144 + tile * 256 + t;
    float acc[64];
#pragma unroll
    for (int c = 0; c < 64; ++c) acc[c] = 0.f;
    for (int ci = 0; ci < 64; ++ci) {
        float hv = s[(size_t)ci * 4096];
        const float* wr = W + ci * 64;
#pragma unroll
        for (int c = 0; c < 64; ++c) acc[c] += hv * wr[c];
    }
    float* d = dst + (size_t)p * 262144 + tile * 256 + t;
    for (int c = 0; c < 64; ++c) {
        float v = acc[c] + B[c];
        if (do_gelu) v = gelu_f(v);
        d[(size_t)c * 4096] = v;
    }
}

// ---------------- inverse x + inverse y + add skip + gelu ----------------
__global__ __launch_bounds__(256) void inv_kernel(
    const float* __restrict__ Fo, const float* __restrict__ WY2,
    float* __restrict__ dst_h, int do_gelu)
{
    __shared__ float tw[128];
    int t = threadIdx.x;
    if (t < 64) {
        float a = TWOPI_F * (float)t / 64.f;
        tw[2 * t] = cosf(a);
        tw[2 * t + 1] = sinf(a);
    }
    __syncthreads();
    int wid = __builtin_amdgcn_readfirstlane((int)(blockIdx.x * 4) + (t >> 6));
    int p = wid >> 6, co = wid & 63;
    int x = t & 63;
    const float* fo = Fo + (size_t)p * 65536 + (size_t)co * 1024;
    float Tr[16], Ti[16];
#pragma unroll
    for (int k = 0; k < 16; ++k) { Tr[k] = 0.f; Ti[k] = 0.f; }
    for (int kxm = 0; kxm < 32; ++kxm) {
        int kx = kxm < 16 ? kxm : kxm + 32;
        int idx = (kx * x) & 63;
        float c_ = tw[2 * idx], s_ = tw[2 * idx + 1];
        const float* fr = fo + kxm * 32;
#pragma unroll
        for (int k = 0; k < 16; ++k) {
            float vr = fr[2 * k], vi = fr[2 * k + 1];
            Tr[k] += vr * c_ - vi * s_;
            Ti[k] += vr * s_ + vi * c_;
        }
    }
    float* out = dst_h + (size_t)p * 262144 + (size_t)co * 4096 + (size_t)x * 64;
    for (int yc = 0; yc < 8; ++yc) {
        float vals[8];
#pragma unroll
        for (int j = 0; j < 8; ++j) {
            int y = yc * 8 + j;
            const float* wr = WY2 + y * 32;
            float acc = 0.f;
#pragma unroll
            for (int k = 0; k < 16; ++k) acc += Tr[k] * wr[2 * k] - Ti[k] * wr[2 * k + 1];
            vals[j] = acc;
        }
#pragma unroll
        for (int j = 0; j < 8; ++j) {
            float v = out[yc * 8 + j] + vals[j];
            if (do_gelu) v = gelu_f(v);
            vals[j] = v;
        }
        *(float4*)(out + yc * 8)     = make_float4(vals[0], vals[1], vals[2], vals[3]);
        *(float4*)(out + yc * 8 + 4) = make_float4(vals[4], vals[5], vals[6], vals[7]);
    }
}

// ---------------- proj2 + weighted accumulate ----------------
__global__ __launch_bounds__(256) void proj2_kernel(
    const float* __restrict__ hsrc, const float* __restrict__ p2w, const float* __restrict__ p2b,
    const int* __restrict__ pair_b, const int* __restrict__ pair_e,
    const float* __restrict__ pw, float* __restrict__ out)
{
    int p = blockIdx.x, tile = blockIdx.y, t = threadIdx.x;
    int b = pair_b[p], e = pair_e[p];
    float wgt = pw[p];
    const float* h = hsrc + (size_t)p * 262144 + tile * 256 + t;
    const float* w2 = p2w + e * 64;
    float acc = p2b[e];
#pragma unroll
    for (int c = 0; c < 64; ++c) acc += h[(size_t)c * 4096] * w2[c];
    atomicAdd(out + (size_t)b * 4096 + tile * 256 + t, wgt * acc);
}

// ---------------- launch ----------------
extern "C" void kernel_launch(void* const* d_in, const int* in_sizes, int n_in,
                              void* d_out, int out_size, void* d_ws, size_t ws_size,
                              hipStream_t stream) {
    const float* x    = (const float*)d_in[0];
    const float* encw = (const float*)d_in[1];
    const float* encb = (const float*)d_in[2];
    const float* wqkv = (const float*)d_in[3];
    const float* bqkv = (const float*)d_in[4];
    const float* wo   = (const float*)d_in[5];
    const float* bo   = (const float*)d_in[6];
    const float* ln1g = (const float*)d_in[7];
    const float* ln1b = (const float*)d_in[8];
    const float* fw1  = (const float*)d_in[9];
    const float* fb1  = (const float*)d_in[10];
    const float* fw2  = (const float*)d_in[11];
    const float* fb2  = (const float*)d_in[12];
    const float* ln2g = (const float*)d_in[13];
    const float* ln2b = (const float*)d_in[14];
    const float* fcw  = (const float*)d_in[15];
    const float* fcb  = (const float*)d_in[16];
    const float* lw   = (const float*)d_in[17];
    const float* lb   = (const float*)d_in[18];
    const float* sw1  = (const float*)d_in[19];
    const float* sw2  = (const float*)d_in[20];
    const float* skw  = (const float*)d_in[21];
    const float* skb  = (const float*)d_in[22];
    const float* p1w  = (const float*)d_in[23];
    const float* p1b  = (const float*)d_in[24];
    const float* p2w  = (const float*)d_in[25];
    const float* p2b  = (const float*)d_in[26];
    float* out = (float*)d_out;

    float* wsf    = (float*)d_ws;
    float* rw     = wsf;               // 256
    float* pair_w = wsf + 256;         // 64
    int*   ipart  = (int*)(wsf + 320);
    int* pair_b = ipart;               // 64
    int* pair_e = ipart + 64;          // 64
    int* estart = ipart + 128;         // 9
    float* Wy  = wsf + 512;            // 2048
    float* TWX = wsf + 2560;           // 4096
    float* WY2 = wsf + 6656;           // 2048
    float* hA  = wsf + 16384;                       // 64 * 262144
    float* hB  = hA + (size_t)64 * 262144;          // 64 * 262144
    float* F   = hB + (size_t)64 * 262144;          // 64 * 65536
    float* G   = F + (size_t)64 * 65536;            // 64 * 131072 (Fo aliases G)
    float* Fo  = G;
    size_t need = (16384 + 2ull * 64 * 262144 + 64ull * 65536 + 64ull * 131072) * 4;
    if (ws_size < need) return;

    hipMemsetAsync(d_out, 0, (size_t)out_size * sizeof(float), stream);
    init_tables_kernel<<<1, 256, 0, stream>>>(Wy, TWX, WY2);
    router_kernel<<<32, 256, 0, stream>>>(x, encw, encb, wqkv, bqkv, wo, bo, ln1g, ln1b,
                                          fw1, fb1, fw2, fb2, ln2g, ln2b, fcw, fcb, rw);
    build_pairs_kernel<<<1, 64, 0, stream>>>(rw, pair_b, pair_e, pair_w, estart);
    lift_kernel<<<dim3(64, 16), 256, 0, stream>>>(x, lw, lb, pair_b, pair_e, hA);
    for (int l = 0; l < 4; ++l) {
        float* cur = (l & 1) ? hB : hA;
        float* nxt = (l & 1) ? hA : hB;
        ydft_kernel<<<1024, 256, 0, stream>>>(cur, Wy, G);
        xdft_kernel<<<512, 256, 0, stream>>>(G, TWX, F);
        spectral_kernel<<<dim3(8, 32, 2), 256, 0, stream>>>(F, Fo, sw1, sw2, estart, l);
        conv1x1_kernel<<<dim3(64, 16), 256, 0, stream>>>(cur, nxt, skw, skb, pair_e, 4, l, 0);
        inv_kernel<<<1024, 256, 0, stream>>>(Fo, WY2, nxt, (l < 3) ? 1 : 0);
    }
    conv1x1_kernel<<<dim3(64, 16), 256, 0, stream>>>(hA, hB, p1w, p1b, pair_e, 1, 0, 1);
    proj2_kernel<<<dim3(64, 16), 256, 0, stream>>>(hB, p2w, p2b, pair_b, pair_e, pair_w, out);
}

// Round 3
// 3303.651 us; speedup vs baseline: 1.4466x; 1.1574x over previous
//
#include <hip/hip_runtime.h>
#include <math.h>

#define TWOPI_F 6.283185307179586f

__device__ __forceinline__ float gelu_f(float v) {
    float u = 0.7978845608028654f * (v + 0.044715f * v * v * v);
    return 0.5f * v * (1.f + tanhf(u));
}

// ---------------- twiddle tables ----------------
__global__ void init_tables_kernel(float* __restrict__ Wy, float* __restrict__ TWX,
                                   float* __restrict__ WY2) {
    int t = threadIdx.x;
    for (int i = t; i < 1024; i += 256) {
        int y = i >> 4, k = i & 15;
        int m = (k * y) & 63;
        float a = -TWOPI_F * (float)m / 64.f;
        Wy[y * 32 + 2 * k]     = cosf(a);
        Wy[y * 32 + 2 * k + 1] = sinf(a);
    }
    for (int i = t; i < 2048; i += 256) {
        int x = i >> 5, kxm = i & 31;
        int kx = kxm < 16 ? kxm : kxm + 32;
        int m = (kx * x) & 63;
        float a = -TWOPI_F * (float)m / 64.f;
        TWX[x * 64 + 2 * kxm]     = cosf(a);
        TWX[x * 64 + 2 * kxm + 1] = sinf(a);
    }
    for (int i = t; i < 1024; i += 256) {
        int y = i >> 4, k = i & 15;
        int m = (k * y) & 63;
        float a = TWOPI_F * (float)m / 64.f;
        float sc = (k == 0 ? 1.f : 2.f) / 4096.f;
        WY2[y * 32 + 2 * k]     = sc * cosf(a);
        WY2[y * 32 + 2 * k + 1] = sc * sinf(a);
    }
}

// ---------------- router: one block per batch ----------------
__global__ __launch_bounds__(256) void router_kernel(
    const float* __restrict__ x, const float* __restrict__ enc_w, const float* __restrict__ enc_b,
    const float* __restrict__ wqkv, const float* __restrict__ bqkv,
    const float* __restrict__ wo, const float* __restrict__ bo,
    const float* __restrict__ ln1g, const float* __restrict__ ln1b,
    const float* __restrict__ w1, const float* __restrict__ b1,
    const float* __restrict__ w2, const float* __restrict__ b2,
    const float* __restrict__ ln2g, const float* __restrict__ ln2b,
    const float* __restrict__ fcw, const float* __restrict__ fcb,
    float* __restrict__ rw)
{
    __shared__ float s[64][64];
    __shared__ float bufA[64][192];
    __shared__ float bufB[64][64];
    __shared__ float bufC[64][64];
    __shared__ float feat[64];
    __shared__ float logits[8];
    int b = blockIdx.x, t = threadIdx.x;

    for (int i = t; i < 4096; i += 256) {
        int w_ = i >> 6, d = i & 63;
        s[w_][d] = x[b * 4096 + w_] * enc_w[d] + enc_b[d];
    }
    __syncthreads();

    for (int l = 0; l < 2; ++l) {
        const float* Wq = wqkv + l * 64 * 192;
        const float* Bq = bqkv + l * 192;
        for (int i = t; i < 64 * 192; i += 256) {
            int r = i / 192, c = i % 192;
            float acc = Bq[c];
            for (int k = 0; k < 64; ++k) acc += s[r][k] * Wq[k * 192 + c];
            bufA[r][c] = acc;
        }
        __syncthreads();
        for (int h = 0; h < 4; ++h) {
            for (int i = t; i < 4096; i += 256) {
                int qi = i >> 6, kj = i & 63;
                float acc = 0.f;
                for (int d = 0; d < 16; ++d)
                    acc += bufA[qi][h * 16 + d] * bufA[kj][64 + h * 16 + d];
                bufB[qi][kj] = acc * 0.25f;
            }
            __syncthreads();
            if (t < 64) {
                float m = -1e30f;
                for (int j = 0; j < 64; ++j) m = fmaxf(m, bufB[t][j]);
                float sum = 0.f;
                for (int j = 0; j < 64; ++j) { float e2 = expf(bufB[t][j] - m); bufB[t][j] = e2; sum += e2; }
                float inv = 1.f / sum;
                for (int j = 0; j < 64; ++j) bufB[t][j] *= inv;
            }
            __syncthreads();
            for (int i = t; i < 1024; i += 256) {
                int qi = i >> 4, d = i & 15;
                float acc = 0.f;
                for (int j = 0; j < 64; ++j) acc += bufB[qi][j] * bufA[j][128 + h * 16 + d];
                bufC[qi][h * 16 + d] = acc;
            }
            __syncthreads();
        }
        const float* Wo = wo + l * 4096;
        const float* Bo = bo + l * 64;
        for (int i = t; i < 4096; i += 256) {
            int r = i >> 6, c = i & 63;
            float acc = Bo[c];
            for (int k = 0; k < 64; ++k) acc += bufC[r][k] * Wo[k * 64 + c];
            bufB[r][c] = s[r][c] + acc;
        }
        __syncthreads();
        if (t < 64) {
            float m = 0.f;
            for (int j = 0; j < 64; ++j) m += bufB[t][j];
            m *= (1.f / 64.f);
            float v = 0.f;
            for (int j = 0; j < 64; ++j) { float d = bufB[t][j] - m; v += d * d; }
            v *= (1.f / 64.f);
            float inv = rsqrtf(v + 1e-5f);
            for (int j = 0; j < 64; ++j)
                s[t][j] = (bufB[t][j] - m) * inv * ln1g[l * 64 + j] + ln1b[l * 64 + j];
        }
        __syncthreads();
        const float* W1 = w1 + l * 64 * 256;
        const float* B1 = b1 + l * 256;
        for (int i = t; i < 64 * 256; i += 256) {
            int r = i >> 8, c = i & 255;
            float acc = B1[c];
            for (int k = 0; k < 64; ++k) acc += s[r][k] * W1[k * 256 + c];
            acc = fmaxf(acc, 0.f);
            if (c < 192) bufA[r][c] = acc; else bufB[r][c - 192] = acc;
        }
        __syncthreads();
        const float* W2 = w2 + l * 256 * 64;
        const float* B2 = b2 + l * 64;
        for (int i = t; i < 4096; i += 256) {
            int r = i >> 6, c = i & 63;
            float acc = B2[c];
            for (int k = 0; k < 256; ++k) {
                float hv = (k < 192) ? bufA[r][k] : bufB[r][k - 192];
                acc += hv * W2[k * 64 + c];
            }
            bufC[r][c] = s[r][c] + acc;
        }
        __syncthreads();
        if (t < 64) {
            float m = 0.f;
            for (int j = 0; j < 64; ++j) m += bufC[t][j];
            m *= (1.f / 64.f);
            float v = 0.f;
            for (int j = 0; j < 64; ++j) { float d = bufC[t][j] - m; v += d * d; }
            v *= (1.f / 64.f);
            float inv = rsqrtf(v + 1e-5f);
            for (int j = 0; j < 64; ++j)
                s[t][j] = (bufC[t][j] - m) * inv * ln2g[l * 64 + j] + ln2b[l * 64 + j];
        }
        __syncthreads();
    }
    if (t < 64) {
        float m = -1e30f;
        for (int r = 0; r < 64; ++r) m = fmaxf(m, s[r][t]);
        feat[t] = m;
    }
    __syncthreads();
    if (t < 8) {
        float acc = fcb[t];
        for (int k = 0; k < 64; ++k) acc += feat[k] * fcw[k * 8 + t];
        logits[t] = acc;
    }
    __syncthreads();
    if (t == 0) {
        int i0 = 0;
        for (int j = 1; j < 8; ++j) if (logits[j] > logits[i0]) i0 = j;
        int i1 = -1;
        for (int j = 0; j < 8; ++j) {
            if (j == i0) continue;
            if (i1 < 0 || logits[j] > logits[i1]) i1 = j;
        }
        float e1 = expf(logits[i1] - logits[i0]);
        float w0 = 1.f / (1.f + e1);
        float w1v = e1 / (1.f + e1);
        for (int j = 0; j < 8; ++j) rw[b * 8 + j] = 0.f;
        rw[b * 8 + i0] = w0;
        rw[b * 8 + i1] = w1v;
    }
}

// ---------------- build compact (b,e) pair list grouped by expert ----------------
__global__ void build_pairs_kernel(const float* __restrict__ rw, int* __restrict__ pair_b,
                                   int* __restrict__ pair_e, float* __restrict__ pair_w,
                                   int* __restrict__ estart) {
    __shared__ float r[256];
    __shared__ int cnt[8], off[9];
    int t = threadIdx.x;
    for (int i = t; i < 256; i += 64) r[i] = rw[i];
    if (t < 64) { pair_b[t] = 0; pair_e[t] = 0; pair_w[t] = 0.f; }
    __syncthreads();
    if (t < 8) {
        int c = 0;
        for (int b = 0; b < 32; ++b) if (r[b * 8 + t] != 0.f) ++c;
        cnt[t] = c;
    }
    __syncthreads();
    if (t == 0) {
        int a = 0;
        for (int e = 0; e < 8; ++e) { off[e] = a; a += cnt[e]; }
        off[8] = a;
        for (int e = 0; e <= 8; ++e) estart[e] = off[e];
    }
    __syncthreads();
    if (t < 8) {
        int n = off[t];
        for (int b = 0; b < 32; ++b) {
            float w = r[b * 8 + t];
            if (w != 0.f) { pair_b[n] = b; pair_e[n] = t; pair_w[n] = w; ++n; }
        }
    }
}

// ---------------- lift ----------------
__global__ __launch_bounds__(256) void lift_kernel(const float* __restrict__ x,
    const float* __restrict__ lw, const float* __restrict__ lb,
    const int* __restrict__ pair_b, const int* __restrict__ pair_e, float* __restrict__ hA) {
    int p = blockIdx.x, tile = blockIdx.y, t = threadIdx.x;
    int b = pair_b[p], e = pair_e[p];
    float* h = hA + (size_t)p * 262144;
    const float* xb = x + (size_t)b * 4096;
    for (int i = tile * 16384 + t; i < (tile + 1) * 16384; i += 256) {
        int co = i >> 12, xy = i & 4095;
        h[i] = xb[xy] * lw[e * 64 + co] + lb[e * 64 + co];
    }
}

// ---------------- forward y-DFT ----------------
__global__ __launch_bounds__(256) void ydft_kernel(const float* __restrict__ h,
    const float* __restrict__ Wy, float* __restrict__ G) {
    int row = blockIdx.x * 256 + threadIdx.x;  // (p,ci,x) = 262144 rows
    const float* src = h + (size_t)row * 64;
    float acc[32];
#pragma unroll
    for (int c = 0; c < 32; ++c) acc[c] = 0.f;
    for (int yc = 0; yc < 4; ++yc) {
        float4 r0 = *(const float4*)(src + yc * 16);
        float4 r1 = *(const float4*)(src + yc * 16 + 4);
        float4 r2 = *(const float4*)(src + yc * 16 + 8);
        float4 r3 = *(const float4*)(src + yc * 16 + 12);
        float rr[16] = {r0.x, r0.y, r0.z, r0.w, r1.x, r1.y, r1.z, r1.w,
                        r2.x, r2.y, r2.z, r2.w, r3.x, r3.y, r3.z, r3.w};
        const float* wb = Wy + yc * 16 * 32;
#pragma unroll
        for (int j = 0; j < 16; ++j) {
            float a = rr[j];
            const float* wr = wb + j * 32;
#pragma unroll
            for (int c = 0; c < 32; ++c) acc[c] += a * wr[c];
        }
    }
    float* dst = G + (size_t)row * 32;
#pragma unroll
    for (int c = 0; c < 32; c += 4)
        *(float4*)(dst + c) = make_float4(acc[c], acc[c + 1], acc[c + 2], acc[c + 3]);
}

// ---------------- forward x-DFT: kx split in halves, 512 blocks ----------------
__global__ __launch_bounds__(256) void xdft_kernel(const float* __restrict__ G,
    const float* __restrict__ TWX, float* __restrict__ F) {
    int gid = blockIdx.x * 256 + threadIdx.x;  // 131072 threads
    int kxh = gid >> 16;
    int rid = gid & 65535;
    int p = rid >> 10, ci = (rid >> 4) & 63, ky = rid & 15;
    const float* gbase = G + (size_t)(p * 64 + ci) * 2048 + ky * 2;
    float ar[16], ai[16];
#pragma unroll
    for (int c = 0; c < 16; ++c) { ar[c] = 0.f; ai[c] = 0.f; }
    for (int xc = 0; xc < 8; ++xc) {
        float gr[8], gi[8];
#pragma unroll
        for (int j = 0; j < 8; ++j) {
            float2 v = *(const float2*)(gbase + (size_t)(xc * 8 + j) * 32);
            gr[j] = v.x; gi[j] = v.y;
        }
#pragma unroll
        for (int j = 0; j < 8; ++j) {
            const float* tx = TWX + (xc * 8 + j) * 64 + kxh * 32;
#pragma unroll
            for (int k = 0; k < 16; ++k) {
                float c_ = tx[2 * k], s_ = tx[2 * k + 1];
                ar[k] += gr[j] * c_ - gi[j] * s_;
                ai[k] += gr[j] * s_ + gi[j] * c_;
            }
        }
    }
    float* fb = F + (size_t)(p * 64 + ci) * 1024 + kxh * 512 + ky * 2;
#pragma unroll
    for (int k = 0; k < 16; ++k) { fb[k * 32] = ar[k]; fb[k * 32 + 1] = ai[k]; }
}

// ---------------- spectral multiply v3: mode-coalesced streaming ----------------
// grid (8 e, 16 co-groups, 4 = wsel x ci-half), block = 4 waves (one co each).
// Lane i owns mode-floats [8i, 8i+8) of the 512-float (ci,co) weight chunk,
// which has the SAME [kx_local][ky][2] ordering as F/Fo half-rows -> both
// global streams perfectly coalesced, complex mult is lane-elementwise.
// ci split in two halves -> partial sums in FoA / FoB (summed in inv_kernel).
__global__ __launch_bounds__(256) void spectral_kernel(
    const float* __restrict__ F, float* __restrict__ FoA, float* __restrict__ FoB,
    const float* __restrict__ w1, const float* __restrict__ w2,
    const int* __restrict__ estart, int l)
{
    int e = blockIdx.x;
    int z = blockIdx.z;
    int wsel = z & 1, cih = z >> 1;
    int p0 = estart[e], ne = estart[e + 1] - p0;
    if (ne == 0) return;
    int t = threadIdx.x;
    int co = blockIdx.y * 4 + (t >> 6);
    int lane = t & 63;

    const float* wbase = (wsel == 0 ? w1 : w2) + (size_t)(e * 4 + l) * 2097152;
    const float* Wc = wbase + (size_t)(cih * 32) * 32768 + (size_t)co * 512 + lane * 8;
    const float* Fc0 = F + (size_t)p0 * 65536 + (size_t)(cih * 32) * 1024 + wsel * 512 + lane * 8;
    float* Fob = (cih ? FoB : FoA) + (size_t)p0 * 65536 + (size_t)co * 1024 + wsel * 512 + lane * 8;

    for (int pc = 0; pc < ne; pc += 8) {
        int np = ne - pc; if (np > 8) np = 8;
        float4 a0[8], a1[8];
#pragma unroll
        for (int p = 0; p < 8; ++p) {
            a0[p] = make_float4(0.f, 0.f, 0.f, 0.f);
            a1[p] = make_float4(0.f, 0.f, 0.f, 0.f);
        }
        const float* Wp = Wc;
        const float* Fp = Fc0 + (size_t)pc * 65536;
        for (int ci = 0; ci < 32; ++ci) {
            float4 wa = *(const float4*)(Wp);
            float4 wb = *(const float4*)(Wp + 4);
#pragma unroll
            for (int p = 0; p < 8; ++p) {
                // p >= np reads in-workspace garbage (never stored) - keeps indexing static
                const float* fp = Fp + (size_t)p * 65536;
                float4 fa = *(const float4*)(fp);
                float4 fb = *(const float4*)(fp + 4);
                a0[p].x += fa.x * wa.x - fa.y * wa.y;
                a0[p].y += fa.x * wa.y + fa.y * wa.x;
                a0[p].z += fa.z * wa.z - fa.w * wa.w;
                a0[p].w += fa.z * wa.w + fa.w * wa.z;
                a1[p].x += fb.x * wb.x - fb.y * wb.y;
                a1[p].y += fb.x * wb.y + fb.y * wb.x;
                a1[p].z += fb.z * wb.z - fb.w * wb.w;
                a1[p].w += fb.z * wb.w + fb.w * wb.z;
            }
            Wp += 32768;
            Fp += 1024;
        }
#pragma unroll
        for (int p = 0; p < 8; ++p) {
            if (p < np) {
                float* d = Fob + (size_t)(pc + p) * 65536;
                *(float4*)(d) = a0[p];
                *(float4*)(d + 4) = a1[p];
            }
        }
    }
}

// ---------------- 1x1 conv (skip / proj1) ----------------
__global__ __launch_bounds__(256) void conv1x1_kernel(
    const float* __restrict__ src, float* __restrict__ dst,
    const float* __restrict__ Wall, const float* __restrict__ Ball,
    const int* __restrict__ pair_e, int wmul, int wadd, int do_gelu)
{
    int p = blockIdx.x, tile = blockIdx.y, t = threadIdx.x;
    int e = pair_e[p];
    int widx = e * wmul + wadd;
    const float* W = Wall + (size_t)widx * 4096;
    const float* B = Ball + widx * 64;
    const float* s = src + (size_t)p * 262144 + tile * 256 + t;
    float acc[64];
#pragma unroll
    for (int c = 0; c < 64; ++c) acc[c] = 0.f;
    for (int ci = 0; ci < 64; ++ci) {
        float hv = s[(size_t)ci * 4096];
        const float* wr = W + ci * 64;
#pragma unroll
        for (int c = 0; c < 64; ++c) acc[c] += hv * wr[c];
    }
    float* d = dst + (size_t)p * 262144 + tile * 256 + t;
    for (int c = 0; c < 64; ++c) {
        float v = acc[c] + B[c];
        if (do_gelu) v = gelu_f(v);
        d[(size_t)c * 4096] = v;
    }
}

// ---------------- inverse x + inverse y + add skip + gelu ----------------
__global__ __launch_bounds__(256) void inv_kernel(
    const float* __restrict__ FoA, const float* __restrict__ FoB,
    const float* __restrict__ WY2, float* __restrict__ dst_h, int do_gelu)
{
    __shared__ float tw[128];
    int t = threadIdx.x;
    if (t < 64) {
        float a = TWOPI_F * (float)t / 64.f;
        tw[2 * t] = cosf(a);
        tw[2 * t + 1] = sinf(a);
    }
    __syncthreads();
    int wid = __builtin_amdgcn_readfirstlane((int)(blockIdx.x * 4) + (t >> 6));
    int p = wid >> 6, co = wid & 63;
    int x = t & 63;
    const float* foA = FoA + (size_t)p * 65536 + (size_t)co * 1024;
    const float* foB = FoB + (size_t)p * 65536 + (size_t)co * 1024;
    float Tr[16], Ti[16];
#pragma unroll
    for (int k = 0; k < 16; ++k) { Tr[k] = 0.f; Ti[k] = 0.f; }
    for (int kxm = 0; kxm < 32; ++kxm) {
        int kx = kxm < 16 ? kxm : kxm + 32;
        int idx = (kx * x) & 63;
        float c_ = tw[2 * idx], s_ = tw[2 * idx + 1];
        const float* frA = foA + kxm * 32;
        const float* frB = foB + kxm * 32;
#pragma unroll
        for (int k = 0; k < 16; ++k) {
            float vr = frA[2 * k] + frB[2 * k];
            float vi = frA[2 * k + 1] + frB[2 * k + 1];
            Tr[k] += vr * c_ - vi * s_;
            Ti[k] += vr * s_ + vi * c_;
        }
    }
    float* out = dst_h + (size_t)p * 262144 + (size_t)co * 4096 + (size_t)x * 64;
    for (int yc = 0; yc < 8; ++yc) {
        float vals[8];
#pragma unroll
        for (int j = 0; j < 8; ++j) {
            int y = yc * 8 + j;
            const float* wr = WY2 + y * 32;
            float acc = 0.f;
#pragma unroll
            for (int k = 0; k < 16; ++k) acc += Tr[k] * wr[2 * k] - Ti[k] * wr[2 * k + 1];
            vals[j] = acc;
        }
#pragma unroll
        for (int j = 0; j < 8; ++j) {
            float v = out[yc * 8 + j] + vals[j];
            if (do_gelu) v = gelu_f(v);
            vals[j] = v;
        }
        *(float4*)(out + yc * 8)     = make_float4(vals[0], vals[1], vals[2], vals[3]);
        *(float4*)(out + yc * 8 + 4) = make_float4(vals[4], vals[5], vals[6], vals[7]);
    }
}

// ---------------- proj2 + weighted accumulate ----------------
__global__ __launch_bounds__(256) void proj2_kernel(
    const float* __restrict__ hsrc, const float* __restrict__ p2w, const float* __restrict__ p2b,
    const int* __restrict__ pair_b, const int* __restrict__ pair_e,
    const float* __restrict__ pw, float* __restrict__ out)
{
    int p = blockIdx.x, tile = blockIdx.y, t = threadIdx.x;
    int b = pair_b[p], e = pair_e[p];
    float wgt = pw[p];
    const float* h = hsrc + (size_t)p * 262144 + tile * 256 + t;
    const float* w2 = p2w + e * 64;
    float acc = p2b[e];
#pragma unroll
    for (int c = 0; c < 64; ++c) acc += h[(size_t)c * 4096] * w2[c];
    atomicAdd(out + (size_t)b * 4096 + tile * 256 + t, wgt * acc);
}

// ---------------- launch ----------------
extern "C" void kernel_launch(void* const* d_in, const int* in_sizes, int n_in,
                              void* d_out, int out_size, void* d_ws, size_t ws_size,
                              hipStream_t stream) {
    const float* x    = (const float*)d_in[0];
    const float* encw = (const float*)d_in[1];
    const float* encb = (const float*)d_in[2];
    const float* wqkv = (const float*)d_in[3];
    const float* bqkv = (const float*)d_in[4];
    const float* wo   = (const float*)d_in[5];
    const float* bo   = (const float*)d_in[6];
    const float* ln1g = (const float*)d_in[7];
    const float* ln1b = (const float*)d_in[8];
    const float* fw1  = (const float*)d_in[9];
    const float* fb1  = (const float*)d_in[10];
    const float* fw2  = (const float*)d_in[11];
    const float* fb2  = (const float*)d_in[12];
    const float* ln2g = (const float*)d_in[13];
    const float* ln2b = (const float*)d_in[14];
    const float* fcw  = (const float*)d_in[15];
    const float* fcb  = (const float*)d_in[16];
    const float* lw   = (const float*)d_in[17];
    const float* lb   = (const float*)d_in[18];
    const float* sw1  = (const float*)d_in[19];
    const float* sw2  = (const float*)d_in[20];
    const float* skw  = (const float*)d_in[21];
    const float* skb  = (const float*)d_in[22];
    const float* p1w  = (const float*)d_in[23];
    const float* p1b  = (const float*)d_in[24];
    const float* p2w  = (const float*)d_in[25];
    const float* p2b  = (const float*)d_in[26];
    float* out = (float*)d_out;

    float* wsf    = (float*)d_ws;
    float* rw     = wsf;               // 256
    float* pair_w = wsf + 256;         // 64
    int*   ipart  = (int*)(wsf + 320);
    int* pair_b = ipart;               // 64
    int* pair_e = ipart + 64;          // 64
    int* estart = ipart + 128;         // 9
    float* Wy  = wsf + 512;            // 2048
    float* TWX = wsf + 2560;           // 4096
    float* WY2 = wsf + 6656;           // 2048
    float* hA  = wsf + 16384;                       // 64 * 262144
    float* hB  = hA + (size_t)64 * 262144;          // 64 * 262144
    float* F   = hB + (size_t)64 * 262144;          // 64 * 65536
    float* G   = F + (size_t)64 * 65536;            // 64 * 131072
    float* FoA = G;                                 // aliases G (free after xdft)
    float* FoB = G + (size_t)64 * 65536;
    size_t need = (16384 + 2ull * 64 * 262144 + 64ull * 65536 + 64ull * 131072) * 4;
    if (ws_size < need) return;

    hipMemsetAsync(d_out, 0, (size_t)out_size * sizeof(float), stream);
    init_tables_kernel<<<1, 256, 0, stream>>>(Wy, TWX, WY2);
    router_kernel<<<32, 256, 0, stream>>>(x, encw, encb, wqkv, bqkv, wo, bo, ln1g, ln1b,
                                          fw1, fb1, fw2, fb2, ln2g, ln2b, fcw, fcb, rw);
    build_pairs_kernel<<<1, 64, 0, stream>>>(rw, pair_b, pair_e, pair_w, estart);
    lift_kernel<<<dim3(64, 16), 256, 0, stream>>>(x, lw, lb, pair_b, pair_e, hA);
    for (int l = 0; l < 4; ++l) {
        float* cur = (l & 1) ? hB : hA;
        float* nxt = (l & 1) ? hA : hB;
        ydft_kernel<<<1024, 256, 0, stream>>>(cur, Wy, G);
        xdft_kernel<<<512, 256, 0, stream>>>(G, TWX, F);
        spectral_kernel<<<dim3(8, 16, 4), 256, 0, stream>>>(F, FoA, FoB, sw1, sw2, estart, l);
        conv1x1_kernel<<<dim3(64, 16), 256, 0, stream>>>(cur, nxt, skw, skb, pair_e, 4, l, 0);
        inv_kernel<<<1024, 256, 0, stream>>>(FoA, FoB, WY2, nxt, (l < 3) ? 1 : 0);
    }
    conv1x1_kernel<<<dim3(64, 16), 256, 0, stream>>>(hA, hB, p1w, p1b, pair_e, 1, 0, 1);
    proj2_kernel<<<dim3(64, 16), 256, 0, stream>>>(hB, p2w, p2b, pair_b, pair_e, pair_w, out);
}

// Round 5
// 2577.611 us; speedup vs baseline: 1.8541x; 1.2817x over previous
//
#include <hip/hip_runtime.h>
#include <math.h>

#define TWOPI_F 6.283185307179586f

__device__ __forceinline__ float gelu_f(float v) {
    float u = 0.7978845608028654f * (v + 0.044715f * v * v * v);
    return 0.5f * v * (1.f + tanhf(u));
}

// ---------------- twiddle tables ----------------
__global__ void init_tables_kernel(float* __restrict__ Wy, float* __restrict__ TWX,
                                   float* __restrict__ WY2) {
    int t = threadIdx.x;
    for (int i = t; i < 1024; i += 256) {
        int y = i >> 4, k = i & 15;
        int m = (k * y) & 63;
        float a = -TWOPI_F * (float)m / 64.f;
        Wy[y * 32 + 2 * k]     = cosf(a);
        Wy[y * 32 + 2 * k + 1] = sinf(a);
    }
    for (int i = t; i < 2048; i += 256) {
        int x = i >> 5, kxm = i & 31;
        int kx = kxm < 16 ? kxm : kxm + 32;
        int m = (kx * x) & 63;
        float a = -TWOPI_F * (float)m / 64.f;
        TWX[x * 64 + 2 * kxm]     = cosf(a);
        TWX[x * 64 + 2 * kxm + 1] = sinf(a);
    }
    for (int i = t; i < 1024; i += 256) {
        int y = i >> 4, k = i & 15;
        int m = (k * y) & 63;
        float a = TWOPI_F * (float)m / 64.f;
        float sc = (k == 0 ? 1.f : 2.f) / 4096.f;
        WY2[y * 32 + 2 * k]     = sc * cosf(a);
        WY2[y * 32 + 2 * k + 1] = sc * sinf(a);
    }
}

// ---------------- router v2: 512 threads, padded LDS, float4 weights ----------------
__global__ __launch_bounds__(512) void router_kernel(
    const float* __restrict__ x, const float* __restrict__ enc_w, const float* __restrict__ enc_b,
    const float* __restrict__ wqkv, const float* __restrict__ bqkv,
    const float* __restrict__ wo, const float* __restrict__ bo,
    const float* __restrict__ ln1g, const float* __restrict__ ln1b,
    const float* __restrict__ w1, const float* __restrict__ b1,
    const float* __restrict__ w2, const float* __restrict__ b2,
    const float* __restrict__ ln2g, const float* __restrict__ ln2b,
    const float* __restrict__ fcw, const float* __restrict__ fcb,
    float* __restrict__ rw)
{
    __shared__ float s[64][65];     // state (padded: bank-free row access)
    __shared__ float qk[64][193];   // qkv / ffn-hidden cols 0..191
    __shared__ float sc[64][65];    // scores / residual
    __shared__ float o64[64][65];   // attn out / ffn-hidden cols 192..255
    __shared__ float feat[64];
    __shared__ float logits[8];
    int b = blockIdx.x, t = threadIdx.x;

    for (int i = t; i < 4096; i += 512) {
        int w_ = i >> 6, d = i & 63;
        s[w_][d] = x[b * 4096 + w_] * enc_w[d] + enc_b[d];
    }
    __syncthreads();

    for (int l = 0; l < 2; ++l) {
        const float* Wq = wqkv + l * 64 * 192;
        const float* Bq = bqkv + l * 192;
        // QKV: 64 rows x 48 float4 cols
        for (int i = t; i < 3072; i += 512) {
            int r = i / 48, c4 = i % 48;
            float4 acc = *(const float4*)(Bq + 4 * c4);
#pragma unroll 8
            for (int k = 0; k < 64; ++k) {
                float sv = s[r][k];
                float4 wv = *(const float4*)(Wq + k * 192 + 4 * c4);
                acc.x += sv * wv.x; acc.y += sv * wv.y;
                acc.z += sv * wv.z; acc.w += sv * wv.w;
            }
            qk[r][4 * c4]     = acc.x; qk[r][4 * c4 + 1] = acc.y;
            qk[r][4 * c4 + 2] = acc.z; qk[r][4 * c4 + 3] = acc.w;
        }
        __syncthreads();
        for (int h = 0; h < 4; ++h) {
            for (int i = t; i < 4096; i += 512) {
                int q = i >> 6, kj = i & 63;
                float acc = 0.f;
#pragma unroll
                for (int d = 0; d < 16; ++d)
                    acc += qk[q][h * 16 + d] * qk[kj][64 + h * 16 + d];
                sc[q][kj] = acc * 0.25f;
            }
            __syncthreads();
            if (t < 64) {  // softmax, row t (padded stride 65: conflict-free)
                float m = -1e30f;
                for (int j = 0; j < 64; ++j) m = fmaxf(m, sc[t][j]);
                float sum = 0.f;
                for (int j = 0; j < 64; ++j) { float e2 = expf(sc[t][j] - m); sc[t][j] = e2; sum += e2; }
                float inv = 1.f / sum;
                for (int j = 0; j < 64; ++j) sc[t][j] *= inv;
            }
            __syncthreads();
            for (int i = t; i < 1024; i += 512) {
                int q = i >> 4, d = i & 15;
                float acc = 0.f;
#pragma unroll 8
                for (int j = 0; j < 64; ++j) acc += sc[q][j] * qk[j][128 + h * 16 + d];
                o64[q][h * 16 + d] = acc;
            }
            __syncthreads();
        }
        // attn proj + residual -> sc
        const float* Wo = wo + l * 4096;
        const float* Bo = bo + l * 64;
        for (int i = t; i < 1024; i += 512) {
            int r = i >> 4, c4 = i & 15;
            float4 acc = *(const float4*)(Bo + 4 * c4);
#pragma unroll 8
            for (int k = 0; k < 64; ++k) {
                float ov = o64[r][k];
                float4 wv = *(const float4*)(Wo + k * 64 + 4 * c4);
                acc.x += ov * wv.x; acc.y += ov * wv.y;
                acc.z += ov * wv.z; acc.w += ov * wv.w;
            }
            sc[r][4 * c4]     = s[r][4 * c4]     + acc.x;
            sc[r][4 * c4 + 1] = s[r][4 * c4 + 1] + acc.y;
            sc[r][4 * c4 + 2] = s[r][4 * c4 + 2] + acc.z;
            sc[r][4 * c4 + 3] = s[r][4 * c4 + 3] + acc.w;
        }
        __syncthreads();
        if (t < 64) {  // LN1: sc -> s
            float m = 0.f;
            for (int j = 0; j < 64; ++j) m += sc[t][j];
            m *= (1.f / 64.f);
            float v = 0.f;
            for (int j = 0; j < 64; ++j) { float d = sc[t][j] - m; v += d * d; }
            v *= (1.f / 64.f);
            float inv = rsqrtf(v + 1e-5f);
            for (int j = 0; j < 64; ++j)
                s[t][j] = (sc[t][j] - m) * inv * ln1g[l * 64 + j] + ln1b[l * 64 + j];
        }
        __syncthreads();
        // FFN1: s @ W1 (64x256) + relu -> hidden (qk cols 0..191, o64 cols 0..63)
        const float* W1 = w1 + l * 64 * 256;
        const float* B1 = b1 + l * 256;
        for (int i = t; i < 4096; i += 512) {
            int r = i >> 6, c4 = i & 63;
            float4 acc = *(const float4*)(B1 + 4 * c4);
#pragma unroll 8
            for (int k = 0; k < 64; ++k) {
                float sv = s[r][k];
                float4 wv = *(const float4*)(W1 + k * 256 + 4 * c4);
                acc.x += sv * wv.x; acc.y += sv * wv.y;
                acc.z += sv * wv.z; acc.w += sv * wv.w;
            }
            acc.x = fmaxf(acc.x, 0.f); acc.y = fmaxf(acc.y, 0.f);
            acc.z = fmaxf(acc.z, 0.f); acc.w = fmaxf(acc.w, 0.f);
            if (c4 < 48) {
                qk[r][4 * c4] = acc.x; qk[r][4 * c4 + 1] = acc.y;
                qk[r][4 * c4 + 2] = acc.z; qk[r][4 * c4 + 3] = acc.w;
            } else {
                int c = 4 * c4 - 192;
                o64[r][c] = acc.x; o64[r][c + 1] = acc.y;
                o64[r][c + 2] = acc.z; o64[r][c + 3] = acc.w;
            }
        }
        __syncthreads();
        // FFN2 + residual -> sc
        const float* W2 = w2 + l * 256 * 64;
        const float* B2 = b2 + l * 64;
        for (int i = t; i < 1024; i += 512) {
            int r = i >> 4, c4 = i & 15;
            float4 acc = *(const float4*)(B2 + 4 * c4);
#pragma unroll 8
            for (int k = 0; k < 192; ++k) {
                float hv = qk[r][k];
                float4 wv = *(const float4*)(W2 + k * 64 + 4 * c4);
                acc.x += hv * wv.x; acc.y += hv * wv.y;
                acc.z += hv * wv.z; acc.w += hv * wv.w;
            }
#pragma unroll 8
            for (int k = 192; k < 256; ++k) {
                float hv = o64[r][k - 192];
                float4 wv = *(const float4*)(W2 + k * 64 + 4 * c4);
                acc.x += hv * wv.x; acc.y += hv * wv.y;
                acc.z += hv * wv.z; acc.w += hv * wv.w;
            }
            sc[r][4 * c4]     = s[r][4 * c4]     + acc.x;
            sc[r][4 * c4 + 1] = s[r][4 * c4 + 1] + acc.y;
            sc[r][4 * c4 + 2] = s[r][4 * c4 + 2] + acc.z;
            sc[r][4 * c4 + 3] = s[r][4 * c4 + 3] + acc.w;
        }
        __syncthreads();
        if (t < 64) {  // LN2: sc -> s
            float m = 0.f;
            for (int j = 0; j < 64; ++j) m += sc[t][j];
            m *= (1.f / 64.f);
            float v = 0.f;
            for (int j = 0; j < 64; ++j) { float d = sc[t][j] - m; v += d * d; }
            v *= (1.f / 64.f);
            float inv = rsqrtf(v + 1e-5f);
            for (int j = 0; j < 64; ++j)
                s[t][j] = (sc[t][j] - m) * inv * ln2g[l * 64 + j] + ln2b[l * 64 + j];
        }
        __syncthreads();
    }
    if (t < 64) {
        float m = -1e30f;
        for (int r = 0; r < 64; ++r) m = fmaxf(m, s[r][t]);
        feat[t] = m;
    }
    __syncthreads();
    if (t < 8) {
        float acc = fcb[t];
        for (int k = 0; k < 64; ++k) acc += feat[k] * fcw[k * 8 + t];
        logits[t] = acc;
    }
    __syncthreads();
    if (t == 0) {
        int i0 = 0;
        for (int j = 1; j < 8; ++j) if (logits[j] > logits[i0]) i0 = j;
        int i1 = -1;
        for (int j = 0; j < 8; ++j) {
            if (j == i0) continue;
            if (i1 < 0 || logits[j] > logits[i1]) i1 = j;
        }
        float e1 = expf(logits[i1] - logits[i0]);
        float w0 = 1.f / (1.f + e1);
        float w1v = e1 / (1.f + e1);
        for (int j = 0; j < 8; ++j) rw[b * 8 + j] = 0.f;
        rw[b * 8 + i0] = w0;
        rw[b * 8 + i1] = w1v;
    }
}

// ---------------- build compact (b,e) pair list grouped by expert ----------------
__global__ void build_pairs_kernel(const float* __restrict__ rw, int* __restrict__ pair_b,
                                   int* __restrict__ pair_e, float* __restrict__ pair_w,
                                   int* __restrict__ estart) {
    __shared__ float r[256];
    __shared__ int cnt[8], off[9];
    int t = threadIdx.x;
    for (int i = t; i < 256; i += 64) r[i] = rw[i];
    if (t < 64) { pair_b[t] = 0; pair_e[t] = 0; pair_w[t] = 0.f; }
    __syncthreads();
    if (t < 8) {
        int c = 0;
        for (int b = 0; b < 32; ++b) if (r[b * 8 + t] != 0.f) ++c;
        cnt[t] = c;
    }
    __syncthreads();
    if (t == 0) {
        int a = 0;
        for (int e = 0; e < 8; ++e) { off[e] = a; a += cnt[e]; }
        off[8] = a;
        for (int e = 0; e <= 8; ++e) estart[e] = off[e];
    }
    __syncthreads();
    if (t < 8) {
        int n = off[t];
        for (int b = 0; b < 32; ++b) {
            float w = r[b * 8 + t];
            if (w != 0.f) { pair_b[n] = b; pair_e[n] = t; pair_w[n] = w; ++n; }
        }
    }
}

// ---------------- lift ----------------
__global__ __launch_bounds__(256) void lift_kernel(const float* __restrict__ x,
    const float* __restrict__ lw, const float* __restrict__ lb,
    const int* __restrict__ pair_b, const int* __restrict__ pair_e, float* __restrict__ hA) {
    int p = blockIdx.x, tile = blockIdx.y, t = threadIdx.x;
    int b = pair_b[p], e = pair_e[p];
    float* h = hA + (size_t)p * 262144;
    const float* xb = x + (size_t)b * 4096;
    for (int i = tile * 16384 + t; i < (tile + 1) * 16384; i += 256) {
        int co = i >> 12, xy = i & 4095;
        h[i] = xb[xy] * lw[e * 64 + co] + lb[e * 64 + co];
    }
}

// ---------------- fused forward DFT (y then x), one block per (p,ci) ----------------
__global__ __launch_bounds__(256) void fwdft_kernel(const float* __restrict__ h,
    const float* __restrict__ Wy, const float* __restrict__ TWX, float* __restrict__ F) {
    __shared__ float ht[64][68];   // h slab [x][y], padded
    __shared__ float gt[64][36];   // y-DFT out [x][16ky complex], padded
    __shared__ float wy[2048];     // FULL Wy table (64y x 16k x 2)
    __shared__ float twx[4096];    // FULL TWX table (64x x 32kxm x 2)
    int bid = blockIdx.x;          // (p*64 + ci)
    int t = threadIdx.x;
    const float* src = h + (size_t)bid * 4096;
    for (int i = t; i < 1024; i += 256) {
        float4 v = *(const float4*)(src + i * 4);
        int x = (i * 4) >> 6, y = (i * 4) & 63;
        *(float4*)(&ht[x][y]) = v;
    }
    for (int i = t; i < 512; i += 256) *(float4*)(&wy[i * 4]) = *(const float4*)(Wy + i * 4);
    for (int i = t; i < 1024; i += 256) *(float4*)(&twx[i * 4]) = *(const float4*)(TWX + i * 4);
    __syncthreads();
    // phase 1: y-DFT. thread = (x = t>>2, kq = t&3) -> k = 4kq..4kq+3
    {
        int xx = t >> 2, kq = t & 3;
        float gr0 = 0.f, gi0 = 0.f, gr1 = 0.f, gi1 = 0.f;
        float gr2 = 0.f, gi2 = 0.f, gr3 = 0.f, gi3 = 0.f;
#pragma unroll 4
        for (int y = 0; y < 64; ++y) {
            float hv = ht[xx][y];
            float4 w0 = *(const float4*)(&wy[y * 32 + kq * 8]);
            float4 w1 = *(const float4*)(&wy[y * 32 + kq * 8 + 4]);
            gr0 += hv * w0.x; gi0 += hv * w0.y;
            gr1 += hv * w0.z; gi1 += hv * w0.w;
            gr2 += hv * w1.x; gi2 += hv * w1.y;
            gr3 += hv * w1.z; gi3 += hv * w1.w;
        }
        *(float4*)(&gt[xx][kq * 8])     = make_float4(gr0, gi0, gr1, gi1);
        *(float4*)(&gt[xx][kq * 8 + 4]) = make_float4(gr2, gi2, gr3, gi3);
    }
    __syncthreads();
    // phase 2: x-DFT. thread = (kxm = t&31, kyq = t>>5) -> ky = 2kyq, 2kyq+1
    {
        int kxm = t & 31, kyq = t >> 5;
        float ar0 = 0.f, ai0 = 0.f, ar1 = 0.f, ai1 = 0.f;
#pragma unroll 4
        for (int xx = 0; xx < 64; ++xx) {
            float2 tw = *(const float2*)(&twx[xx * 64 + 2 * kxm]);
            float4 g = *(const float4*)(&gt[xx][kyq * 4]);
            ar0 += g.x * tw.x - g.y * tw.y;  ai0 += g.x * tw.y + g.y * tw.x;
            ar1 += g.z * tw.x - g.w * tw.y;  ai1 += g.z * tw.y + g.w * tw.x;
        }
        float* fb = F + (size_t)bid * 1024 + kxm * 32 + kyq * 4;
        *(float4*)(fb) = make_float4(ar0, ai0, ar1, ai1);
    }
}

// ---------------- spectral multiply v3 (unchanged) ----------------
__global__ __launch_bounds__(256) void spectral_kernel(
    const float* __restrict__ F, float* __restrict__ FoA, float* __restrict__ FoB,
    const float* __restrict__ w1, const float* __restrict__ w2,
    const int* __restrict__ estart, int l)
{
    int e = blockIdx.x;
    int z = blockIdx.z;
    int wsel = z & 1, cih = z >> 1;
    int p0 = estart[e], ne = estart[e + 1] - p0;
    if (ne == 0) return;
    int t = threadIdx.x;
    int co = blockIdx.y * 4 + (t >> 6);
    int lane = t & 63;

    const float* wbase = (wsel == 0 ? w1 : w2) + (size_t)(e * 4 + l) * 2097152;
    const float* Wc = wbase + (size_t)(cih * 32) * 32768 + (size_t)co * 512 + lane * 8;
    const float* Fc0 = F + (size_t)p0 * 65536 + (size_t)(cih * 32) * 1024 + wsel * 512 + lane * 8;
    float* Fob = (cih ? FoB : FoA) + (size_t)p0 * 65536 + (size_t)co * 1024 + wsel * 512 + lane * 8;

    for (int pc = 0; pc < ne; pc += 8) {
        int np = ne - pc; if (np > 8) np = 8;
        float4 a0[8], a1[8];
#pragma unroll
        for (int p = 0; p < 8; ++p) {
            a0[p] = make_float4(0.f, 0.f, 0.f, 0.f);
            a1[p] = make_float4(0.f, 0.f, 0.f, 0.f);
        }
        const float* Wp = Wc;
        const float* Fp = Fc0 + (size_t)pc * 65536;
        for (int ci = 0; ci < 32; ++ci) {
            float4 wa = *(const float4*)(Wp);
            float4 wb = *(const float4*)(Wp + 4);
#pragma unroll
            for (int p = 0; p < 8; ++p) {
                const float* fp = Fp + (size_t)p * 65536;
                float4 fa = *(const float4*)(fp);
                float4 fb = *(const float4*)(fp + 4);
                a0[p].x += fa.x * wa.x - fa.y * wa.y;
                a0[p].y += fa.x * wa.y + fa.y * wa.x;
                a0[p].z += fa.z * wa.z - fa.w * wa.w;
                a0[p].w += fa.z * wa.w + fa.w * wa.z;
                a1[p].x += fb.x * wb.x - fb.y * wb.y;
                a1[p].y += fb.x * wb.y + fb.y * wb.x;
                a1[p].z += fb.z * wb.z - fb.w * wb.w;
                a1[p].w += fb.z * wb.w + fb.w * wb.z;
            }
            Wp += 32768;
            Fp += 1024;
        }
#pragma unroll
        for (int p = 0; p < 8; ++p) {
            if (p < np) {
                float* d = Fob + (size_t)(pc + p) * 65536;
                *(float4*)(d) = a0[p];
                *(float4*)(d + 4) = a1[p];
            }
        }
    }
}

// ---------------- 1x1 conv (skip / proj1) ----------------
__global__ __launch_bounds__(256) void conv1x1_kernel(
    const float* __restrict__ src, float* __restrict__ dst,
    const float* __restrict__ Wall, const float* __restrict__ Ball,
    const int* __restrict__ pair_e, int wmul, int wadd, int do_gelu)
{
    int p = blockIdx.x, tile = blockIdx.y, t = threadIdx.x;
    int e = pair_e[p];
    int widx = e * wmul + wadd;
    const float* W = Wall + (size_t)widx * 4096;
    const float* B = Ball + widx * 64;
    const float* s = src + (size_t)p * 262144 + tile * 256 + t;
    float acc[64];
#pragma unroll
    for (int c = 0; c < 64; ++c) acc[c] = 0.f;
    for (int ci = 0; ci < 64; ++ci) {
        float hv = s[(size_t)ci * 4096];
        const float* wr = W + ci * 64;
#pragma unroll
        for (int c = 0; c < 64; ++c) acc[c] += hv * wr[c];
    }
    float* d = dst + (size_t)p * 262144 + tile * 256 + t;
    for (int c = 0; c < 64; ++c) {
        float v = acc[c] + B[c];
        if (do_gelu) v = gelu_f(v);
        d[(size_t)c * 4096] = v;
    }
}

// ---------------- inverse DFT + skip-add + gelu, 4 (p,co) items per block ----------------
__global__ __launch_bounds__(256) void inv_kernel(
    const float* __restrict__ FoA, const float* __restrict__ FoB,
    const float* __restrict__ WY2, float* __restrict__ dst_h, int do_gelu)
{
    __shared__ float wy2[2048];
    __shared__ float twl[128];
    __shared__ float fo_s[1024];
    __shared__ float tT[64][36];
    __shared__ float ot[64][66];
    int t = threadIdx.x;
    for (int i = t; i < 512; i += 256) *(float4*)(&wy2[i * 4]) = *(const float4*)(WY2 + i * 4);
    if (t < 64) {
        float a = TWOPI_F * (float)t / 64.f;
        twl[2 * t] = cosf(a);
        twl[2 * t + 1] = sinf(a);
    }
    __syncthreads();

    for (int item = 0; item < 4; ++item) {
        int wid = blockIdx.x * 4 + item;
        int p = wid >> 6, co = wid & 63;
        const float* fA = FoA + (size_t)p * 65536 + (size_t)co * 1024;
        const float* fB = FoB + (size_t)p * 65536 + (size_t)co * 1024;
        {
            float4 a = *(const float4*)(fA + t * 4);
            float4 b = *(const float4*)(fB + t * 4);
            *(float4*)(&fo_s[t * 4]) = make_float4(a.x + b.x, a.y + b.y, a.z + b.z, a.w + b.w);
        }
        __syncthreads();
        // T-compute: thread (xx = t&63, kq = t>>6) -> k = 4kq..4kq+3
        {
            int xx = t & 63, kq = t >> 6;
            float Tr0 = 0.f, Ti0 = 0.f, Tr1 = 0.f, Ti1 = 0.f;
            float Tr2 = 0.f, Ti2 = 0.f, Tr3 = 0.f, Ti3 = 0.f;
#pragma unroll 4
            for (int kxm = 0; kxm < 32; ++kxm) {
                int kx = kxm < 16 ? kxm : kxm + 32;
                int idx = (kx * xx) & 63;
                float c_ = twl[2 * idx], s_ = twl[2 * idx + 1];
                float4 f0 = *(const float4*)(&fo_s[kxm * 32 + kq * 8]);
                float4 f1 = *(const float4*)(&fo_s[kxm * 32 + kq * 8 + 4]);
                Tr0 += f0.x * c_ - f0.y * s_;  Ti0 += f0.x * s_ + f0.y * c_;
                Tr1 += f0.z * c_ - f0.w * s_;  Ti1 += f0.z * s_ + f0.w * c_;
                Tr2 += f1.x * c_ - f1.y * s_;  Ti2 += f1.x * s_ + f1.y * c_;
                Tr3 += f1.z * c_ - f1.w * s_;  Ti3 += f1.z * s_ + f1.w * c_;
            }
            *(float4*)(&tT[xx][kq * 8])     = make_float4(Tr0, Ti0, Tr1, Ti1);
            *(float4*)(&tT[xx][kq * 8 + 4]) = make_float4(Tr2, Ti2, Tr3, Ti3);
        }
        __syncthreads();
        // synthesis: thread (xx = t&63, yq = t>>6) -> y = 16yq..16yq+15
        {
            int xx = t & 63, yq = t >> 6;
            float Trr[16], Tii[16];
#pragma unroll
            for (int q = 0; q < 8; ++q) {
                float4 v = *(const float4*)(&tT[xx][q * 4]);
                Trr[q * 2] = v.x; Tii[q * 2] = v.y;
                Trr[q * 2 + 1] = v.z; Tii[q * 2 + 1] = v.w;
            }
            for (int j = 0; j < 16; ++j) {
                int y = yq * 16 + j;
                const float* wr = &wy2[y * 32];
                float acc = 0.f;
#pragma unroll
                for (int k = 0; k < 16; ++k)
                    acc += Trr[k] * wr[2 * k] - Tii[k] * wr[2 * k + 1];
                ot[xx][y] = acc;
            }
        }
        __syncthreads();
        // coalesced read-modify-write of dst (skip already there) + gelu
        {
            float* base = dst_h + (size_t)p * 262144 + (size_t)co * 4096;
            for (int r = 0; r < 16; ++r) {
                int gidx = r * 256 + t;
                int xx = gidx >> 6, y = gidx & 63;
                float v = base[gidx] + ot[xx][y];
                if (do_gelu) v = gelu_f(v);
                base[gidx] = v;
            }
        }
        __syncthreads();
    }
}

// ---------------- proj2 + weighted accumulate ----------------
__global__ __launch_bounds__(256) void proj2_kernel(
    const float* __restrict__ hsrc, const float* __restrict__ p2w, const float* __restrict__ p2b,
    const int* __restrict__ pair_b, const int* __restrict__ pair_e,
    const float* __restrict__ pw, float* __restrict__ out)
{
    int p = blockIdx.x, tile = blockIdx.y, t = threadIdx.x;
    int b = pair_b[p], e = pair_e[p];
    float wgt = pw[p];
    const float* h = hsrc + (size_t)p * 262144 + tile * 256 + t;
    const float* w2 = p2w + e * 64;
    float acc = p2b[e];
#pragma unroll
    for (int c = 0; c < 64; ++c) acc += h[(size_t)c * 4096] * w2[c];
    atomicAdd(out + (size_t)b * 4096 + tile * 256 + t, wgt * acc);
}

// ---------------- launch ----------------
extern "C" void kernel_launch(void* const* d_in, const int* in_sizes, int n_in,
                              void* d_out, int out_size, void* d_ws, size_t ws_size,
                              hipStream_t stream) {
    const float* x    = (const float*)d_in[0];
    const float* encw = (const float*)d_in[1];
    const float* encb = (const float*)d_in[2];
    const float* wqkv = (const float*)d_in[3];
    const float* bqkv = (const float*)d_in[4];
    const float* wo   = (const float*)d_in[5];
    const float* bo   = (const float*)d_in[6];
    const float* ln1g = (const float*)d_in[7];
    const float* ln1b = (const float*)d_in[8];
    const float* fw1  = (const float*)d_in[9];
    const float* fb1  = (const float*)d_in[10];
    const float* fw2  = (const float*)d_in[11];
    const float* fb2  = (const float*)d_in[12];
    const float* ln2g = (const float*)d_in[13];
    const float* ln2b = (const float*)d_in[14];
    const float* fcw  = (const float*)d_in[15];
    const float* fcb  = (const float*)d_in[16];
    const float* lw   = (const float*)d_in[17];
    const float* lb   = (const float*)d_in[18];
    const float* sw1  = (const float*)d_in[19];
    const float* sw2  = (const float*)d_in[20];
    const float* skw  = (const float*)d_in[21];
    const float* skb  = (const float*)d_in[22];
    const float* p1w  = (const float*)d_in[23];
    const float* p1b  = (const float*)d_in[24];
    const float* p2w  = (const float*)d_in[25];
    const float* p2b  = (const float*)d_in[26];
    float* out = (float*)d_out;

    float* wsf    = (float*)d_ws;
    float* rw     = wsf;               // 256
    float* pair_w = wsf + 256;         // 64
    int*   ipart  = (int*)(wsf + 320);
    int* pair_b = ipart;               // 64
    int* pair_e = ipart + 64;          // 64
    int* estart = ipart + 128;         // 9
    float* Wy  = wsf + 512;            // 2048
    float* TWX = wsf + 2560;           // 4096
    float* WY2 = wsf + 6656;           // 2048
    float* hA  = wsf + 16384;                       // 64 * 262144
    float* hB  = hA + (size_t)64 * 262144;          // 64 * 262144
    float* F   = hB + (size_t)64 * 262144;          // 64 * 65536
    float* FoA = F + (size_t)64 * 65536;            // 64 * 65536
    float* FoB = FoA + (size_t)64 * 65536;          // 64 * 65536
    size_t need = (16384 + 2ull * 64 * 262144 + 64ull * 65536 + 64ull * 131072) * 4;
    if (ws_size < need) return;

    hipMemsetAsync(d_out, 0, (size_t)out_size * sizeof(float), stream);
    init_tables_kernel<<<1, 256, 0, stream>>>(Wy, TWX, WY2);
    router_kernel<<<32, 512, 0, stream>>>(x, encw, encb, wqkv, bqkv, wo, bo, ln1g, ln1b,
                                          fw1, fb1, fw2, fb2, ln2g, ln2b, fcw, fcb, rw);
    build_pairs_kernel<<<1, 64, 0, stream>>>(rw, pair_b, pair_e, pair_w, estart);
    lift_kernel<<<dim3(64, 16), 256, 0, stream>>>(x, lw, lb, pair_b, pair_e, hA);
    for (int l = 0; l < 4; ++l) {
        float* cur = (l & 1) ? hB : hA;
        float* nxt = (l & 1) ? hA : hB;
        fwdft_kernel<<<4096, 256, 0, stream>>>(cur, Wy, TWX, F);
        spectral_kernel<<<dim3(8, 16, 4), 256, 0, stream>>>(F, FoA, FoB, sw1, sw2, estart, l);
        conv1x1_kernel<<<dim3(64, 16), 256, 0, stream>>>(cur, nxt, skw, skb, pair_e, 4, l, 0);
        inv_kernel<<<1024, 256, 0, stream>>>(FoA, FoB, WY2, nxt, (l < 3) ? 1 : 0);
    }
    conv1x1_kernel<<<dim3(64, 16), 256, 0, stream>>>(hA, hB, p1w, p1b, pair_e, 1, 0, 1);
    proj2_kernel<<<dim3(64, 16), 256, 0, stream>>>(hB, p2w, p2b, pair_b, pair_e, pair_w, out);
}